// Round 1
// baseline (358.324 us; speedup 1.0000x reference)
//
#include <hip/hip_runtime.h>

#define SPHN 9
#define CHN 64

// ---------------------------------------------------------------------------
// Setup: compute real Wigner J matrices (l=1: 3x3 at Jout[0..8], l=2: 5x5 at
// Jout[9..33]) in double precision, exact transcription of the reference's
// _small_d / _real_J.
// ---------------------------------------------------------------------------
__global__ void k_setup_J(float* __restrict__ Jout)
{
    if (blockIdx.x != 0 || threadIdx.x != 0) return;
    double fact[9];
    fact[0] = 1.0;
    for (int i = 1; i < 9; ++i) fact[i] = fact[i - 1] * (double)i;
    const double is2 = 0.70710678118654752440; // 1/sqrt(2) == cos(pi/4) == sin(pi/4)
    int outoff = 0;
    for (int l = 1; l <= 2; ++l) {
        const int n = 2 * l + 1;
        double d[5][5];
        for (int mp = -l; mp <= l; ++mp)
            for (int m = -l; m <= l; ++m) {
                double val = 0.0;
                int k0 = (m - mp) > 0 ? (m - mp) : 0;
                int k1 = (l + m < l - mp) ? (l + m) : (l - mp);
                for (int k = k0; k <= k1; ++k) {
                    double sign = ((mp - m + k) & 1) ? -1.0 : 1.0;
                    double num = sign * sqrt(fact[l + mp] * fact[l - mp] * fact[l + m] * fact[l - m]);
                    double den = fact[l + m - k] * fact[k] * fact[mp - m + k] * fact[l - mp - k];
                    double cp = 1.0;
                    for (int q = 0; q < 2 * l + m - mp - 2 * k; ++q) cp *= is2;
                    double sp = 1.0;
                    for (int q = 0; q < mp - m + 2 * k; ++q) sp *= is2;
                    val += num / den * cp * sp;
                }
                d[mp + l][m + l] = val;
            }
        double Cre[5][5] = {{0}}, Cim[5][5] = {{0}};
        for (int m = -l; m <= l; ++m) {
            if (m == 0) {
                Cre[l][l] = 1.0;
            } else if (m > 0) {
                Cre[m + l][-m + l] = is2;
                Cre[m + l][m + l] = ((m & 1) ? -1.0 : 1.0) * is2;
            } else {
                Cim[m + l][m + l] = is2;
                Cim[m + l][-m + l] = -(((m & 1)) ? -1.0 : 1.0) * is2;
            }
        }
        // T = d @ C^H  ; T[i][j] = sum_k d[i][k] * conj(C[j][k])
        double Tre[5][5], Tim[5][5];
        for (int i = 0; i < n; ++i)
            for (int j = 0; j < n; ++j) {
                double tr = 0.0, ti = 0.0;
                for (int k = 0; k < n; ++k) {
                    tr += d[i][k] * Cre[j][k];
                    ti -= d[i][k] * Cim[j][k];
                }
                Tre[i][j] = tr;
                Tim[i][j] = ti;
            }
        // J = Re(C @ T)
        for (int i = 0; i < n; ++i)
            for (int j = 0; j < n; ++j) {
                double jr = 0.0;
                for (int k = 0; k < n; ++k)
                    jr += Cre[i][k] * Tre[k][j] - Cim[i][k] * Tim[k][j];
                Jout[outoff + i * n + j] = (float)jr;
            }
        outoff += n * n;
    }
}

// ---------------------------------------------------------------------------
// Per-node: xm = node_feats @ W_msg1, keep only needed SPH rows {1,3,4,5,7,8}
// ---------------------------------------------------------------------------
__global__ __launch_bounds__(64) void k_xm(const float* __restrict__ nf,
                                           const float* __restrict__ m1,
                                           float* __restrict__ xm6)
{
    const int n = blockIdx.x;
    const int t = threadIdx.x;
    __shared__ float sx[SPHN * CHN];
    const float* xp = nf + (size_t)n * (SPHN * CHN);
#pragma unroll
    for (int i = 0; i < 9; ++i) sx[i * 64 + t] = xp[i * 64 + t];
    __syncthreads();
    float a0 = 0.f, a1 = 0.f, a2 = 0.f, a3 = 0.f, a4 = 0.f, a5 = 0.f;
    for (int c = 0; c < 64; ++c) {
        float m = m1[c * 64 + t];
        a0 += sx[1 * 64 + c] * m;
        a1 += sx[3 * 64 + c] * m;
        a2 += sx[4 * 64 + c] * m;
        a3 += sx[5 * 64 + c] * m;
        a4 += sx[7 * 64 + c] * m;
        a5 += sx[8 * 64 + c] * m;
    }
    float* op = xm6 + (size_t)n * 384;
    op[0 * 64 + t] = a0;
    op[1 * 64 + t] = a1;
    op[2 * 64 + t] = a2;
    op[3 * 64 + t] = a3;
    op[4 * 64 + t] = a4;
    op[5 * 64 + t] = a5;
}

// ---------------------------------------------------------------------------
// Wigner block entry W[i][j] for angle pair (bA, cA):
//   W = Z(0) . (J . Z(bA) . J) . Z(cA)
// with the reference's quirky z-rot: diag cos((l-i)a), antidiag sin((l-i)a),
// center element = sin(0) = 0 (overwrites the cos).
// ---------------------------------------------------------------------------
__device__ __forceinline__ float wig_entry(int l, int i, int j, float bA, float cA,
                                           const float* __restrict__ J, int n)
{
    if (i == l) return 0.f;
    const int j2 = 2 * l - j;
    float Pij = 0.f, Pij2 = 0.f;
    for (int k = 0; k < n; ++k) {
        float sbk, cbk;
        __sincosf((float)(l - k) * bA, &sbk, &cbk);
        if (k == l) cbk = 0.f;
        float zj  = cbk * J[k * n + j]  + sbk * J[(2 * l - k) * n + j];
        float zj2 = cbk * J[k * n + j2] + sbk * J[(2 * l - k) * n + j2];
        Pij  += J[i * n + k] * zj;
        Pij2 += J[i * n + k] * zj2;
    }
    float s_, c_;
    __sincosf((float)(l - j) * cA, &s_, &c_);
    float czj = (j == l) ? 0.f : c_;
    float szj = -s_; // sin((j-l)*cA)
    return Pij * czj + Pij2 * szj;
}

__device__ __forceinline__ float siluf(float x) { return x / (1.f + expf(-x)); }

// ---------------------------------------------------------------------------
// Per-edge kernel: one wave (64 threads) per edge.
// ---------------------------------------------------------------------------
__global__ __launch_bounds__(64) void k_edge(const float* __restrict__ evec,
                                             const int* __restrict__ eidx,
                                             const float* __restrict__ w1,
                                             const float* __restrict__ b1,
                                             const float* __restrict__ w2,
                                             const float* __restrict__ Jc,
                                             const float* __restrict__ xm6,
                                             float* __restrict__ acc, int E)
{
    const int e = blockIdx.x;
    const int t = threadIdx.x;
    __shared__ float s_rbf[64];
    __shared__ float s_h[128];
    __shared__ float s_W1[9], s_W2[25], s_Q1[9], s_Q2[25];

    float vx = evec[(size_t)e * 3 + 0];
    float vy = evec[(size_t)e * 3 + 1];
    float vz = evec[(size_t)e * 3 + 2];
    float dist = sqrtf(vx * vx + vy * vy + vz * vz);
    float inv = 1.0f / fmaxf(dist, 1e-7f);
    float xn = fminf(fmaxf(vx * inv, -1.f), 1.f);
    float yn = fminf(fmaxf(vy * inv, -1.f), 1.f);
    float zn = fminf(fmaxf(vz * inv, -1.f), 1.f);
    float beta = acosf(fminf(fmaxf(yn, -1.f + 1e-7f), 1.f - 1e-7f));
    float alpha = atan2f(xn, zn);
    float bA = -beta;   // wigner beta arg  = -beta
    float cA = -alpha;  // wigner gamma arg = -alpha

    // --- RBF ---
    const float step = 6.0f / 63.0f;
    float diff = dist - step * (float)t;
    s_rbf[t] = expf(-55.125f * diff * diff); // coeff = -0.5/step^2
    __syncthreads();

    // --- hidden layer: lane t computes h[t], h[t+64] ---
    float h0 = b1[t], h1 = b1[64 + t];
    for (int k = 0; k < 64; ++k) {
        float r = s_rbf[k];
        h0 += r * w1[k * 128 + t];
        h1 += r * w1[k * 128 + 64 + t];
    }
    s_h[t] = siluf(h0);
    s_h[64 + t] = siluf(h1);
    __syncthreads();

    // --- rad[t] ---
    float rad = 0.f;
    for (int j = 0; j < 128; ++j) rad += s_h[j] * w2[j * 64 + t];
    float dd = dist * (1.0f / 6.0f);
    float env = 0.f;
    if (dd < 1.0f) {
        float d2 = dd * dd;
        float d5 = d2 * d2 * dd;
        env = 1.0f - 21.0f * d5 + 35.0f * d5 * dd - 15.0f * d5 * d2;
    }
    rad *= env;

    // --- Wigner blocks ---
    if (t < 25) {
        s_W2[t] = wig_entry(2, t / 5, t % 5, bA, cA, Jc + 9, 5);
    } else if (t >= 32 && t < 41) {
        int u = t - 32;
        s_W1[u] = wig_entry(1, u / 3, u % 3, bA, cA, Jc, 3);
    }
    __syncthreads();

    // --- Q = W^T W ---
    if (t < 25) {
        int i = t / 5, j = t % 5;
        float q = 0.f;
#pragma unroll
        for (int k = 0; k < 5; ++k) q += s_W2[k * 5 + i] * s_W2[k * 5 + j];
        s_Q2[t] = q;
    } else if (t >= 32 && t < 41) {
        int u = t - 32;
        int i = u / 3, j = u % 3;
        float q = 0.f;
#pragma unroll
        for (int k = 0; k < 3; ++k) q += s_W1[k * 3 + i] * s_W1[k * 3 + j];
        s_Q1[u] = q;
    }
    __syncthreads();

    // --- gather, sparse Q transform, scale, scatter ---
    const int src = eidx[e];
    const int dst = eidx[E + e];
    const float* xs = xm6 + (size_t)src * 384;
    float x1 = xs[0 * 64 + t];
    float x3 = xs[1 * 64 + t];
    float x4 = xs[2 * 64 + t];
    float x5 = xs[3 * 64 + t];
    float x7 = xs[4 * 64 + t];
    float x8 = xs[5 * 64 + t];

    float m1v = rad * (s_Q1[0] * x1 + s_Q1[2] * x3);
    float m3v = rad * (s_Q1[6] * x1 + s_Q1[8] * x3);
    float m4v = rad * (s_Q2[0]  * x4 + s_Q2[1]  * x5 + s_Q2[3]  * x7 + s_Q2[4]  * x8);
    float m5v = rad * (s_Q2[5]  * x4 + s_Q2[6]  * x5 + s_Q2[8]  * x7 + s_Q2[9]  * x8);
    float m7v = rad * (s_Q2[15] * x4 + s_Q2[16] * x5 + s_Q2[18] * x7 + s_Q2[19] * x8);
    float m8v = rad * (s_Q2[20] * x4 + s_Q2[21] * x5 + s_Q2[23] * x7 + s_Q2[24] * x8);

    float* ad = acc + (size_t)dst * 576;
    atomicAdd(ad + 1 * 64 + t, m1v);
    atomicAdd(ad + 3 * 64 + t, m3v);
    atomicAdd(ad + 4 * 64 + t, m4v);
    atomicAdd(ad + 5 * 64 + t, m5v);
    atomicAdd(ad + 7 * 64 + t, m7v);
    atomicAdd(ad + 8 * 64 + t, m8v);
}

// ---------------------------------------------------------------------------
// Per-node finalize (in place on d_out): v = acc @ W_msg2, RMS over SPH axis
// (per node,channel), scale by gamma. Rows 0,2,6 are identically zero.
// ---------------------------------------------------------------------------
__global__ __launch_bounds__(64) void k_fin(const float* __restrict__ m2,
                                            const float* __restrict__ gam,
                                            float* __restrict__ out)
{
    const int n = blockIdx.x;
    const int t = threadIdx.x;
    __shared__ float sa[6 * 64];
    float* op = out + (size_t)n * 576;
    sa[0 * 64 + t] = op[1 * 64 + t];
    sa[1 * 64 + t] = op[3 * 64 + t];
    sa[2 * 64 + t] = op[4 * 64 + t];
    sa[3 * 64 + t] = op[5 * 64 + t];
    sa[4 * 64 + t] = op[7 * 64 + t];
    sa[5 * 64 + t] = op[8 * 64 + t];
    __syncthreads();
    float v0 = 0.f, v1 = 0.f, v2 = 0.f, v3 = 0.f, v4 = 0.f, v5 = 0.f;
    for (int c = 0; c < 64; ++c) {
        float m = m2[c * 64 + t];
        v0 += sa[0 * 64 + c] * m;
        v1 += sa[1 * 64 + c] * m;
        v2 += sa[2 * 64 + c] * m;
        v3 += sa[3 * 64 + c] * m;
        v4 += sa[4 * 64 + c] * m;
        v5 += sa[5 * 64 + c] * m;
    }
    float ss = v0 * v0 + v1 * v1 + v2 * v2 + v3 * v3 + v4 * v4 + v5 * v5;
    float rms = sqrtf(ss * (1.0f / 9.0f) + 1e-7f);
    float sc = gam[t] / rms;
    op[0 * 64 + t] = 0.f;
    op[2 * 64 + t] = 0.f;
    op[6 * 64 + t] = 0.f;
    op[1 * 64 + t] = v0 * sc;
    op[3 * 64 + t] = v1 * sc;
    op[4 * 64 + t] = v2 * sc;
    op[5 * 64 + t] = v3 * sc;
    op[7 * 64 + t] = v4 * sc;
    op[8 * 64 + t] = v5 * sc;
}

extern "C" void kernel_launch(void* const* d_in, const int* in_sizes, int n_in,
                              void* d_out, int out_size, void* d_ws, size_t ws_size,
                              hipStream_t stream)
{
    const float* nf  = (const float*)d_in[0];
    const float* ev  = (const float*)d_in[1];
    const int*   ei  = (const int*)d_in[2];
    const float* w1  = (const float*)d_in[3];
    const float* b1  = (const float*)d_in[4];
    const float* w2  = (const float*)d_in[5];
    const float* m1  = (const float*)d_in[6];
    const float* m2  = (const float*)d_in[7];
    const float* gam = (const float*)d_in[8];

    const int N = in_sizes[0] / (SPHN * CHN);
    const int E = in_sizes[1] / 3;

    float* out = (float*)d_out;
    float* Jc  = (float*)d_ws;                       // 34 floats
    float* xm6 = (float*)((char*)d_ws + 256);        // N*6*64 floats

    hipLaunchKernelGGL(k_setup_J, dim3(1), dim3(64), 0, stream, Jc);
    hipLaunchKernelGGL(k_xm, dim3(N), dim3(64), 0, stream, nf, m1, xm6);
    hipMemsetAsync(d_out, 0, (size_t)out_size * sizeof(float), stream);
    hipLaunchKernelGGL(k_edge, dim3(E), dim3(64), 0, stream, ev, ei, w1, b1, w2, Jc, xm6, out, E);
    hipLaunchKernelGGL(k_fin, dim3(N), dim3(64), 0, stream, m2, gam, out);
}

// Round 3
// 306.117 us; speedup vs baseline: 1.1705x; 1.1705x over previous
//
#include <hip/hip_runtime.h>

#define SPHN 9
#define CHN 64

// ---------------------------------------------------------------------------
// Setup: compute real Wigner J matrices (l=1: 3x3 at Jout[0..8], l=2: 5x5 at
// Jout[9..33]) in double precision, exact transcription of the reference's
// _small_d / _real_J.
// ---------------------------------------------------------------------------
__global__ void k_setup_J(float* __restrict__ Jout)
{
    if (blockIdx.x != 0 || threadIdx.x != 0) return;
    double fact[9];
    fact[0] = 1.0;
    for (int i = 1; i < 9; ++i) fact[i] = fact[i - 1] * (double)i;
    const double is2 = 0.70710678118654752440;
    int outoff = 0;
    for (int l = 1; l <= 2; ++l) {
        const int n = 2 * l + 1;
        double d[5][5];
        for (int mp = -l; mp <= l; ++mp)
            for (int m = -l; m <= l; ++m) {
                double val = 0.0;
                int k0 = (m - mp) > 0 ? (m - mp) : 0;
                int k1 = (l + m < l - mp) ? (l + m) : (l - mp);
                for (int k = k0; k <= k1; ++k) {
                    double sign = ((mp - m + k) & 1) ? -1.0 : 1.0;
                    double num = sign * sqrt(fact[l + mp] * fact[l - mp] * fact[l + m] * fact[l - m]);
                    double den = fact[l + m - k] * fact[k] * fact[mp - m + k] * fact[l - mp - k];
                    double cp = 1.0;
                    for (int q = 0; q < 2 * l + m - mp - 2 * k; ++q) cp *= is2;
                    double sp = 1.0;
                    for (int q = 0; q < mp - m + 2 * k; ++q) sp *= is2;
                    val += num / den * cp * sp;
                }
                d[mp + l][m + l] = val;
            }
        double Cre[5][5] = {{0}}, Cim[5][5] = {{0}};
        for (int m = -l; m <= l; ++m) {
            if (m == 0) {
                Cre[l][l] = 1.0;
            } else if (m > 0) {
                Cre[m + l][-m + l] = is2;
                Cre[m + l][m + l] = ((m & 1) ? -1.0 : 1.0) * is2;
            } else {
                Cim[m + l][m + l] = is2;
                Cim[m + l][-m + l] = -(((m & 1)) ? -1.0 : 1.0) * is2;
            }
        }
        double Tre[5][5], Tim[5][5];
        for (int i = 0; i < n; ++i)
            for (int j = 0; j < n; ++j) {
                double tr = 0.0, ti = 0.0;
                for (int k = 0; k < n; ++k) {
                    tr += d[i][k] * Cre[j][k];
                    ti -= d[i][k] * Cim[j][k];
                }
                Tre[i][j] = tr;
                Tim[i][j] = ti;
            }
        for (int i = 0; i < n; ++i)
            for (int j = 0; j < n; ++j) {
                double jr = 0.0;
                for (int k = 0; k < n; ++k)
                    jr += Cre[i][k] * Tre[k][j] - Cim[i][k] * Tim[k][j];
                Jout[outoff + i * n + j] = (float)jr;
            }
        outoff += n * n;
    }
}

// ---------------------------------------------------------------------------
// Per-node: xm = node_feats @ W_msg1, keep only needed SPH rows {1,3,4,5,7,8}
// ---------------------------------------------------------------------------
__global__ __launch_bounds__(64) void k_xm(const float* __restrict__ nf,
                                           const float* __restrict__ m1,
                                           float* __restrict__ xm6)
{
    const int n = blockIdx.x;
    const int t = threadIdx.x;
    __shared__ float sx[SPHN * CHN];
    const float* xp = nf + (size_t)n * (SPHN * CHN);
#pragma unroll
    for (int i = 0; i < 9; ++i) sx[i * 64 + t] = xp[i * 64 + t];
    __syncthreads();
    float a0 = 0.f, a1 = 0.f, a2 = 0.f, a3 = 0.f, a4 = 0.f, a5 = 0.f;
    for (int c = 0; c < 64; ++c) {
        float m = m1[c * 64 + t];
        a0 += sx[1 * 64 + c] * m;
        a1 += sx[3 * 64 + c] * m;
        a2 += sx[4 * 64 + c] * m;
        a3 += sx[5 * 64 + c] * m;
        a4 += sx[7 * 64 + c] * m;
        a5 += sx[8 * 64 + c] * m;
    }
    float* op = xm6 + (size_t)n * 384;
    op[0 * 64 + t] = a0;
    op[1 * 64 + t] = a1;
    op[2 * 64 + t] = a2;
    op[3 * 64 + t] = a3;
    op[4 * 64 + t] = a4;
    op[5 * 64 + t] = a5;
}

__device__ __forceinline__ float siluf(float x) { return x / (1.f + expf(-x)); }

// ---------------------------------------------------------------------------
// Radial MLP as a tiled GEMM: 64 edges per block, 256 threads.
// LDS: rbfT[64k][64e] + hT[128j][64e] + dist/env = 48.5 KB -> 3 blocks/CU.
// Weights stream from global (L1-resident, float4, 4x register reuse).
// ---------------------------------------------------------------------------
__global__ __launch_bounds__(256) void k_rad(const float* __restrict__ evec,
                                             const float* __restrict__ w1,
                                             const float* __restrict__ b1,
                                             const float* __restrict__ w2,
                                             float* __restrict__ radg,
                                             int E)
{
    __shared__ float rbfT[64 * 64];   // [k][e]
    __shared__ float hT[128 * 64];    // [j][e]
    __shared__ float distS[64];
    __shared__ float envS[64];
    const int tid = threadIdx.x;
    const int base = blockIdx.x * 64;

    // Phase A: dist, env
    if (tid < 64) {
        int e = base + tid;
        float dist = 0.f;
        if (e < E) {
            float vx = evec[(size_t)e * 3 + 0];
            float vy = evec[(size_t)e * 3 + 1];
            float vz = evec[(size_t)e * 3 + 2];
            dist = sqrtf(vx * vx + vy * vy + vz * vz);
        }
        distS[tid] = dist;
        float dd = dist * (1.0f / 6.0f);
        float env = 0.f;
        if (dd < 1.0f) {
            float d2 = dd * dd;
            float d5 = d2 * d2 * dd;
            env = 1.0f - 21.0f * d5 + 35.0f * d5 * dd - 15.0f * d5 * d2;
        }
        envS[tid] = env;
    }
    __syncthreads();
    // rbf fill: rbfT[k][e]
    const float step = 6.0f / 63.0f;
#pragma unroll
    for (int p = 0; p < 16; ++p) {
        int idx = p * 256 + tid;
        int k = idx >> 6, e = idx & 63;
        float diff = distS[e] - step * (float)k;
        rbfT[idx] = expf(-55.125f * diff * diff);
    }
    __syncthreads();

    // Phase B: h[64e][128j] = rbf @ W1 + b1, silu, store transposed hT[j][e]
    {
        const int eg = tid >> 4;        // 0..15
        const int jg = tid & 15;        // 0..15
        float hacc[4][8];
        float4 b0 = *(const float4*)&b1[jg * 8];
        float4 b4 = *(const float4*)&b1[jg * 8 + 4];
#pragma unroll
        for (int ee = 0; ee < 4; ++ee) {
            hacc[ee][0] = b0.x; hacc[ee][1] = b0.y; hacc[ee][2] = b0.z; hacc[ee][3] = b0.w;
            hacc[ee][4] = b4.x; hacc[ee][5] = b4.y; hacc[ee][6] = b4.z; hacc[ee][7] = b4.w;
        }
#pragma unroll 4
        for (int k = 0; k < 64; ++k) {
            float4 wa = *(const float4*)&w1[k * 128 + jg * 8];
            float4 wb = *(const float4*)&w1[k * 128 + jg * 8 + 4];
            float4 rb = *(const float4*)&rbfT[k * 64 + eg * 4];
            float r[4] = {rb.x, rb.y, rb.z, rb.w};
#pragma unroll
            for (int ee = 0; ee < 4; ++ee) {
                hacc[ee][0] += r[ee] * wa.x;
                hacc[ee][1] += r[ee] * wa.y;
                hacc[ee][2] += r[ee] * wa.z;
                hacc[ee][3] += r[ee] * wa.w;
                hacc[ee][4] += r[ee] * wb.x;
                hacc[ee][5] += r[ee] * wb.y;
                hacc[ee][6] += r[ee] * wb.z;
                hacc[ee][7] += r[ee] * wb.w;
            }
        }
#pragma unroll
        for (int jj = 0; jj < 8; ++jj) {
            float4 hv;
            hv.x = siluf(hacc[0][jj]);
            hv.y = siluf(hacc[1][jj]);
            hv.z = siluf(hacc[2][jj]);
            hv.w = siluf(hacc[3][jj]);
            *(float4*)&hT[(jg * 8 + jj) * 64 + eg * 4] = hv;
        }
    }
    __syncthreads();

    // Phase C: rad[64e][64t] = silu(h) @ W2, * env
    {
        const int eg = tid >> 4;        // 0..15
        const int tg = tid & 15;        // 0..15
        float acc[4][4];
#pragma unroll
        for (int ee = 0; ee < 4; ++ee)
#pragma unroll
            for (int tt = 0; tt < 4; ++tt) acc[ee][tt] = 0.f;
#pragma unroll 4
        for (int j = 0; j < 128; ++j) {
            float4 wv = *(const float4*)&w2[j * 64 + tg * 4];
            float4 hv = *(const float4*)&hT[j * 64 + eg * 4];
            float h[4] = {hv.x, hv.y, hv.z, hv.w};
#pragma unroll
            for (int ee = 0; ee < 4; ++ee) {
                acc[ee][0] += h[ee] * wv.x;
                acc[ee][1] += h[ee] * wv.y;
                acc[ee][2] += h[ee] * wv.z;
                acc[ee][3] += h[ee] * wv.w;
            }
        }
#pragma unroll
        for (int ee = 0; ee < 4; ++ee) {
            int e = base + eg * 4 + ee;
            if (e < E) {
                float envv = envS[eg * 4 + ee];
                float4 o;
                o.x = acc[ee][0] * envv;
                o.y = acc[ee][1] * envv;
                o.z = acc[ee][2] * envv;
                o.w = acc[ee][3] * envv;
                *(float4*)&radg[(size_t)e * 64 + tg * 4] = o;
            }
        }
    }
}

// ---------------------------------------------------------------------------
// Wigner block entry W[i][j] (reference's quirky z-rot: center element = 0)
// ---------------------------------------------------------------------------
__device__ __forceinline__ float wig_entry(int l, int i, int j, float bA, float cA,
                                           const float* __restrict__ J, int n)
{
    if (i == l) return 0.f;
    const int j2 = 2 * l - j;
    float Pij = 0.f, Pij2 = 0.f;
    for (int k = 0; k < n; ++k) {
        float sbk, cbk;
        __sincosf((float)(l - k) * bA, &sbk, &cbk);
        if (k == l) cbk = 0.f;
        float zj  = cbk * J[k * n + j]  + sbk * J[(2 * l - k) * n + j];
        float zj2 = cbk * J[k * n + j2] + sbk * J[(2 * l - k) * n + j2];
        Pij  += J[i * n + k] * zj;
        Pij2 += J[i * n + k] * zj2;
    }
    float s_, c_;
    __sincosf((float)(l - j) * cA, &s_, &c_);
    float czj = (j == l) ? 0.f : c_;
    float szj = -s_;
    return Pij * czj + Pij2 * szj;
}

// ---------------------------------------------------------------------------
// Slim per-edge kernel: Wigner Q + gather + scale + atomic scatter.
// ---------------------------------------------------------------------------
__global__ __launch_bounds__(64) void k_edge2(const float* __restrict__ evec,
                                              const int* __restrict__ eidx,
                                              const float* __restrict__ radg,
                                              const float* __restrict__ Jc,
                                              const float* __restrict__ xm6,
                                              float* __restrict__ acc, int E)
{
    const int e = blockIdx.x;
    const int t = threadIdx.x;
    __shared__ float s_W1[9], s_W2[25], s_Q1[9], s_Q2[25];

    float vx = evec[(size_t)e * 3 + 0];
    float vy = evec[(size_t)e * 3 + 1];
    float vz = evec[(size_t)e * 3 + 2];
    float dist = sqrtf(vx * vx + vy * vy + vz * vz);
    float inv = 1.0f / fmaxf(dist, 1e-7f);
    float xn = fminf(fmaxf(vx * inv, -1.f), 1.f);
    float yn = fminf(fmaxf(vy * inv, -1.f), 1.f);
    float zn = fminf(fmaxf(vz * inv, -1.f), 1.f);
    float beta = acosf(fminf(fmaxf(yn, -1.f + 1e-7f), 1.f - 1e-7f));
    float alpha = atan2f(xn, zn);
    float bA = -beta;
    float cA = -alpha;

    if (t < 25) {
        s_W2[t] = wig_entry(2, t / 5, t % 5, bA, cA, Jc + 9, 5);
    } else if (t >= 32 && t < 41) {
        int u = t - 32;
        s_W1[u] = wig_entry(1, u / 3, u % 3, bA, cA, Jc, 3);
    }
    __syncthreads();

    if (t < 25) {
        int i = t / 5, j = t % 5;
        float q = 0.f;
#pragma unroll
        for (int k = 0; k < 5; ++k) q += s_W2[k * 5 + i] * s_W2[k * 5 + j];
        s_Q2[t] = q;
    } else if (t >= 32 && t < 41) {
        int u = t - 32;
        int i = u / 3, j = u % 3;
        float q = 0.f;
#pragma unroll
        for (int k = 0; k < 3; ++k) q += s_W1[k * 3 + i] * s_W1[k * 3 + j];
        s_Q1[u] = q;
    }
    __syncthreads();

    const float rad = radg[(size_t)e * 64 + t];
    const int src = eidx[e];
    const int dst = eidx[E + e];
    const float* xs = xm6 + (size_t)src * 384;
    float x1 = xs[0 * 64 + t];
    float x3 = xs[1 * 64 + t];
    float x4 = xs[2 * 64 + t];
    float x5 = xs[3 * 64 + t];
    float x7 = xs[4 * 64 + t];
    float x8 = xs[5 * 64 + t];

    float m1v = rad * (s_Q1[0] * x1 + s_Q1[2] * x3);
    float m3v = rad * (s_Q1[6] * x1 + s_Q1[8] * x3);
    float m4v = rad * (s_Q2[0]  * x4 + s_Q2[1]  * x5 + s_Q2[3]  * x7 + s_Q2[4]  * x8);
    float m5v = rad * (s_Q2[5]  * x4 + s_Q2[6]  * x5 + s_Q2[8]  * x7 + s_Q2[9]  * x8);
    float m7v = rad * (s_Q2[15] * x4 + s_Q2[16] * x5 + s_Q2[18] * x7 + s_Q2[19] * x8);
    float m8v = rad * (s_Q2[20] * x4 + s_Q2[21] * x5 + s_Q2[23] * x7 + s_Q2[24] * x8);

    float* ad = acc + (size_t)dst * 576;
    atomicAdd(ad + 1 * 64 + t, m1v);
    atomicAdd(ad + 3 * 64 + t, m3v);
    atomicAdd(ad + 4 * 64 + t, m4v);
    atomicAdd(ad + 5 * 64 + t, m5v);
    atomicAdd(ad + 7 * 64 + t, m7v);
    atomicAdd(ad + 8 * 64 + t, m8v);
}

// ---------------------------------------------------------------------------
// Fallback fused per-edge kernel (used only if ws too small for rad buffer)
// ---------------------------------------------------------------------------
__global__ __launch_bounds__(64) void k_edge_fused(const float* __restrict__ evec,
                                                   const int* __restrict__ eidx,
                                                   const float* __restrict__ w1,
                                                   const float* __restrict__ b1,
                                                   const float* __restrict__ w2,
                                                   const float* __restrict__ Jc,
                                                   const float* __restrict__ xm6,
                                                   float* __restrict__ acc, int E)
{
    const int e = blockIdx.x;
    const int t = threadIdx.x;
    __shared__ float s_rbf[64];
    __shared__ float s_h[128];
    __shared__ float s_W1[9], s_W2[25], s_Q1[9], s_Q2[25];

    float vx = evec[(size_t)e * 3 + 0];
    float vy = evec[(size_t)e * 3 + 1];
    float vz = evec[(size_t)e * 3 + 2];
    float dist = sqrtf(vx * vx + vy * vy + vz * vz);
    float inv = 1.0f / fmaxf(dist, 1e-7f);
    float xn = fminf(fmaxf(vx * inv, -1.f), 1.f);
    float yn = fminf(fmaxf(vy * inv, -1.f), 1.f);
    float zn = fminf(fmaxf(vz * inv, -1.f), 1.f);
    float beta = acosf(fminf(fmaxf(yn, -1.f + 1e-7f), 1.f - 1e-7f));
    float alpha = atan2f(xn, zn);
    float bA = -beta;
    float cA = -alpha;

    const float step = 6.0f / 63.0f;
    float diff = dist - step * (float)t;
    s_rbf[t] = expf(-55.125f * diff * diff);
    __syncthreads();

    float h0 = b1[t], h1 = b1[64 + t];
    for (int k = 0; k < 64; ++k) {
        float r = s_rbf[k];
        h0 += r * w1[k * 128 + t];
        h1 += r * w1[k * 128 + 64 + t];
    }
    s_h[t] = siluf(h0);
    s_h[64 + t] = siluf(h1);
    __syncthreads();

    float rad = 0.f;
    for (int j = 0; j < 128; ++j) rad += s_h[j] * w2[j * 64 + t];
    float dd = dist * (1.0f / 6.0f);
    float env = 0.f;
    if (dd < 1.0f) {
        float d2 = dd * dd;
        float d5 = d2 * d2 * dd;
        env = 1.0f - 21.0f * d5 + 35.0f * d5 * dd - 15.0f * d5 * d2;
    }
    rad *= env;

    if (t < 25) {
        s_W2[t] = wig_entry(2, t / 5, t % 5, bA, cA, Jc + 9, 5);
    } else if (t >= 32 && t < 41) {
        int u = t - 32;
        s_W1[u] = wig_entry(1, u / 3, u % 3, bA, cA, Jc, 3);
    }
    __syncthreads();

    if (t < 25) {
        int i = t / 5, j = t % 5;
        float q = 0.f;
#pragma unroll
        for (int k = 0; k < 5; ++k) q += s_W2[k * 5 + i] * s_W2[k * 5 + j];
        s_Q2[t] = q;
    } else if (t >= 32 && t < 41) {
        int u = t - 32;
        int i = u / 3, j = u % 3;
        float q = 0.f;
#pragma unroll
        for (int k = 0; k < 3; ++k) q += s_W1[k * 3 + i] * s_W1[k * 3 + j];
        s_Q1[u] = q;
    }
    __syncthreads();

    const int src = eidx[e];
    const int dst = eidx[E + e];
    const float* xs = xm6 + (size_t)src * 384;
    float x1 = xs[0 * 64 + t];
    float x3 = xs[1 * 64 + t];
    float x4 = xs[2 * 64 + t];
    float x5 = xs[3 * 64 + t];
    float x7 = xs[4 * 64 + t];
    float x8 = xs[5 * 64 + t];

    float m1v = rad * (s_Q1[0] * x1 + s_Q1[2] * x3);
    float m3v = rad * (s_Q1[6] * x1 + s_Q1[8] * x3);
    float m4v = rad * (s_Q2[0]  * x4 + s_Q2[1]  * x5 + s_Q2[3]  * x7 + s_Q2[4]  * x8);
    float m5v = rad * (s_Q2[5]  * x4 + s_Q2[6]  * x5 + s_Q2[8]  * x7 + s_Q2[9]  * x8);
    float m7v = rad * (s_Q2[15] * x4 + s_Q2[16] * x5 + s_Q2[18] * x7 + s_Q2[19] * x8);
    float m8v = rad * (s_Q2[20] * x4 + s_Q2[21] * x5 + s_Q2[23] * x7 + s_Q2[24] * x8);

    float* ad = acc + (size_t)dst * 576;
    atomicAdd(ad + 1 * 64 + t, m1v);
    atomicAdd(ad + 3 * 64 + t, m3v);
    atomicAdd(ad + 4 * 64 + t, m4v);
    atomicAdd(ad + 5 * 64 + t, m5v);
    atomicAdd(ad + 7 * 64 + t, m7v);
    atomicAdd(ad + 8 * 64 + t, m8v);
}

// ---------------------------------------------------------------------------
// Per-node finalize (in place on d_out)
// ---------------------------------------------------------------------------
__global__ __launch_bounds__(64) void k_fin(const float* __restrict__ m2,
                                            const float* __restrict__ gam,
                                            float* __restrict__ out)
{
    const int n = blockIdx.x;
    const int t = threadIdx.x;
    __shared__ float sa[6 * 64];
    float* op = out + (size_t)n * 576;
    sa[0 * 64 + t] = op[1 * 64 + t];
    sa[1 * 64 + t] = op[3 * 64 + t];
    sa[2 * 64 + t] = op[4 * 64 + t];
    sa[3 * 64 + t] = op[5 * 64 + t];
    sa[4 * 64 + t] = op[7 * 64 + t];
    sa[5 * 64 + t] = op[8 * 64 + t];
    __syncthreads();
    float v0 = 0.f, v1 = 0.f, v2 = 0.f, v3 = 0.f, v4 = 0.f, v5 = 0.f;
    for (int c = 0; c < 64; ++c) {
        float m = m2[c * 64 + t];
        v0 += sa[0 * 64 + c] * m;
        v1 += sa[1 * 64 + c] * m;
        v2 += sa[2 * 64 + c] * m;
        v3 += sa[3 * 64 + c] * m;
        v4 += sa[4 * 64 + c] * m;
        v5 += sa[5 * 64 + c] * m;
    }
    float ss = v0 * v0 + v1 * v1 + v2 * v2 + v3 * v3 + v4 * v4 + v5 * v5;
    float rms = sqrtf(ss * (1.0f / 9.0f) + 1e-7f);
    float sc = gam[t] / rms;
    op[0 * 64 + t] = 0.f;
    op[2 * 64 + t] = 0.f;
    op[6 * 64 + t] = 0.f;
    op[1 * 64 + t] = v0 * sc;
    op[3 * 64 + t] = v1 * sc;
    op[4 * 64 + t] = v2 * sc;
    op[5 * 64 + t] = v3 * sc;
    op[7 * 64 + t] = v4 * sc;
    op[8 * 64 + t] = v5 * sc;
}

extern "C" void kernel_launch(void* const* d_in, const int* in_sizes, int n_in,
                              void* d_out, int out_size, void* d_ws, size_t ws_size,
                              hipStream_t stream)
{
    const float* nf  = (const float*)d_in[0];
    const float* ev  = (const float*)d_in[1];
    const int*   ei  = (const int*)d_in[2];
    const float* w1  = (const float*)d_in[3];
    const float* b1  = (const float*)d_in[4];
    const float* w2  = (const float*)d_in[5];
    const float* m1  = (const float*)d_in[6];
    const float* m2  = (const float*)d_in[7];
    const float* gam = (const float*)d_in[8];

    const int N = in_sizes[0] / (SPHN * CHN);
    const int E = in_sizes[1] / 3;

    float* out = (float*)d_out;
    float* Jc  = (float*)d_ws;                            // 34 floats
    char*  p   = (char*)d_ws + 256;
    float* xm6 = (float*)p;                               // N*384 floats
    size_t xm6_bytes = (size_t)N * 384 * sizeof(float);
    float* radg = (float*)(p + xm6_bytes);                // E*64 floats
    size_t need = 256 + xm6_bytes + (size_t)E * 64 * sizeof(float);

    hipLaunchKernelGGL(k_setup_J, dim3(1), dim3(64), 0, stream, Jc);
    hipLaunchKernelGGL(k_xm, dim3(N), dim3(64), 0, stream, nf, m1, xm6);
    hipMemsetAsync(d_out, 0, (size_t)out_size * sizeof(float), stream);
    if (ws_size >= need) {
        hipLaunchKernelGGL(k_rad, dim3((E + 63) / 64), dim3(256), 0, stream,
                           ev, w1, b1, w2, radg, E);
        hipLaunchKernelGGL(k_edge2, dim3(E), dim3(64), 0, stream,
                           ev, ei, radg, Jc, xm6, out, E);
    } else {
        hipLaunchKernelGGL(k_edge_fused, dim3(E), dim3(64), 0, stream,
                           ev, ei, w1, b1, w2, Jc, xm6, out, E);
    }
    hipLaunchKernelGGL(k_fin, dim3(N), dim3(64), 0, stream, m2, gam, out);
}

// Round 4
// 273.651 us; speedup vs baseline: 1.3094x; 1.1186x over previous
//
#include <hip/hip_runtime.h>

#define SPHN 9
#define CHN 64

// ---------------------------------------------------------------------------
// Setup: real Wigner J matrices (l=1: 3x3 at Jout[0..8], l=2: 5x5 at
// Jout[9..33]), double precision, exact transcription of reference.
// ---------------------------------------------------------------------------
__global__ void k_setup_J(float* __restrict__ Jout)
{
    if (blockIdx.x != 0 || threadIdx.x != 0) return;
    double fact[9];
    fact[0] = 1.0;
    for (int i = 1; i < 9; ++i) fact[i] = fact[i - 1] * (double)i;
    const double is2 = 0.70710678118654752440;
    int outoff = 0;
    for (int l = 1; l <= 2; ++l) {
        const int n = 2 * l + 1;
        double d[5][5];
        for (int mp = -l; mp <= l; ++mp)
            for (int m = -l; m <= l; ++m) {
                double val = 0.0;
                int k0 = (m - mp) > 0 ? (m - mp) : 0;
                int k1 = (l + m < l - mp) ? (l + m) : (l - mp);
                for (int k = k0; k <= k1; ++k) {
                    double sign = ((mp - m + k) & 1) ? -1.0 : 1.0;
                    double num = sign * sqrt(fact[l + mp] * fact[l - mp] * fact[l + m] * fact[l - m]);
                    double den = fact[l + m - k] * fact[k] * fact[mp - m + k] * fact[l - mp - k];
                    double cp = 1.0;
                    for (int q = 0; q < 2 * l + m - mp - 2 * k; ++q) cp *= is2;
                    double sp = 1.0;
                    for (int q = 0; q < mp - m + 2 * k; ++q) sp *= is2;
                    val += num / den * cp * sp;
                }
                d[mp + l][m + l] = val;
            }
        double Cre[5][5] = {{0}}, Cim[5][5] = {{0}};
        for (int m = -l; m <= l; ++m) {
            if (m == 0) {
                Cre[l][l] = 1.0;
            } else if (m > 0) {
                Cre[m + l][-m + l] = is2;
                Cre[m + l][m + l] = ((m & 1) ? -1.0 : 1.0) * is2;
            } else {
                Cim[m + l][m + l] = is2;
                Cim[m + l][-m + l] = -(((m & 1)) ? -1.0 : 1.0) * is2;
            }
        }
        double Tre[5][5], Tim[5][5];
        for (int i = 0; i < n; ++i)
            for (int j = 0; j < n; ++j) {
                double tr = 0.0, ti = 0.0;
                for (int k = 0; k < n; ++k) {
                    tr += d[i][k] * Cre[j][k];
                    ti -= d[i][k] * Cim[j][k];
                }
                Tre[i][j] = tr;
                Tim[i][j] = ti;
            }
        for (int i = 0; i < n; ++i)
            for (int j = 0; j < n; ++j) {
                double jr = 0.0;
                for (int k = 0; k < n; ++k)
                    jr += Cre[i][k] * Tre[k][j] - Cim[i][k] * Tim[k][j];
                Jout[outoff + i * n + j] = (float)jr;
            }
        outoff += n * n;
    }
}

// ---------------------------------------------------------------------------
// Per-node: xm = node_feats @ W_msg1, only needed SPH rows {1,3,4,5,7,8}
// ---------------------------------------------------------------------------
__global__ __launch_bounds__(64) void k_xm(const float* __restrict__ nf,
                                           const float* __restrict__ m1,
                                           float* __restrict__ xm6)
{
    const int n = blockIdx.x;
    const int t = threadIdx.x;
    __shared__ float sx[SPHN * CHN];
    const float* xp = nf + (size_t)n * (SPHN * CHN);
#pragma unroll
    for (int i = 0; i < 9; ++i) sx[i * 64 + t] = xp[i * 64 + t];
    __syncthreads();
    float a0 = 0.f, a1 = 0.f, a2 = 0.f, a3 = 0.f, a4 = 0.f, a5 = 0.f;
    for (int c = 0; c < 64; ++c) {
        float m = m1[c * 64 + t];
        a0 += sx[1 * 64 + c] * m;
        a1 += sx[3 * 64 + c] * m;
        a2 += sx[4 * 64 + c] * m;
        a3 += sx[5 * 64 + c] * m;
        a4 += sx[7 * 64 + c] * m;
        a5 += sx[8 * 64 + c] * m;
    }
    float* op = xm6 + (size_t)n * 384;
    op[0 * 64 + t] = a0;
    op[1 * 64 + t] = a1;
    op[2 * 64 + t] = a2;
    op[3 * 64 + t] = a3;
    op[4 * 64 + t] = a4;
    op[5 * 64 + t] = a5;
}

__device__ __forceinline__ float siluf(float x) { return x / (1.f + expf(-x)); }

// ---------------------------------------------------------------------------
// Radial MLP tiled GEMM: 64 edges/block, 256 threads.
// ---------------------------------------------------------------------------
__global__ __launch_bounds__(256) void k_rad(const float* __restrict__ evec,
                                             const float* __restrict__ w1,
                                             const float* __restrict__ b1,
                                             const float* __restrict__ w2,
                                             float* __restrict__ radg,
                                             int E)
{
    __shared__ float rbfT[64 * 64];
    __shared__ float hT[128 * 64];
    __shared__ float distS[64];
    __shared__ float envS[64];
    const int tid = threadIdx.x;
    const int base = blockIdx.x * 64;

    if (tid < 64) {
        int e = base + tid;
        float dist = 0.f;
        if (e < E) {
            float vx = evec[(size_t)e * 3 + 0];
            float vy = evec[(size_t)e * 3 + 1];
            float vz = evec[(size_t)e * 3 + 2];
            dist = sqrtf(vx * vx + vy * vy + vz * vz);
        }
        distS[tid] = dist;
        float dd = dist * (1.0f / 6.0f);
        float env = 0.f;
        if (dd < 1.0f) {
            float d2 = dd * dd;
            float d5 = d2 * d2 * dd;
            env = 1.0f - 21.0f * d5 + 35.0f * d5 * dd - 15.0f * d5 * d2;
        }
        envS[tid] = env;
    }
    __syncthreads();
    const float step = 6.0f / 63.0f;
#pragma unroll
    for (int p = 0; p < 16; ++p) {
        int idx = p * 256 + tid;
        int k = idx >> 6, e = idx & 63;
        float diff = distS[e] - step * (float)k;
        rbfT[idx] = expf(-55.125f * diff * diff);
    }
    __syncthreads();

    {
        const int eg = tid >> 4;
        const int jg = tid & 15;
        float hacc[4][8];
        float4 b0 = *(const float4*)&b1[jg * 8];
        float4 b4 = *(const float4*)&b1[jg * 8 + 4];
#pragma unroll
        for (int ee = 0; ee < 4; ++ee) {
            hacc[ee][0] = b0.x; hacc[ee][1] = b0.y; hacc[ee][2] = b0.z; hacc[ee][3] = b0.w;
            hacc[ee][4] = b4.x; hacc[ee][5] = b4.y; hacc[ee][6] = b4.z; hacc[ee][7] = b4.w;
        }
#pragma unroll 4
        for (int k = 0; k < 64; ++k) {
            float4 wa = *(const float4*)&w1[k * 128 + jg * 8];
            float4 wb = *(const float4*)&w1[k * 128 + jg * 8 + 4];
            float4 rb = *(const float4*)&rbfT[k * 64 + eg * 4];
            float r[4] = {rb.x, rb.y, rb.z, rb.w};
#pragma unroll
            for (int ee = 0; ee < 4; ++ee) {
                hacc[ee][0] += r[ee] * wa.x;
                hacc[ee][1] += r[ee] * wa.y;
                hacc[ee][2] += r[ee] * wa.z;
                hacc[ee][3] += r[ee] * wa.w;
                hacc[ee][4] += r[ee] * wb.x;
                hacc[ee][5] += r[ee] * wb.y;
                hacc[ee][6] += r[ee] * wb.z;
                hacc[ee][7] += r[ee] * wb.w;
            }
        }
#pragma unroll
        for (int jj = 0; jj < 8; ++jj) {
            float4 hv;
            hv.x = siluf(hacc[0][jj]);
            hv.y = siluf(hacc[1][jj]);
            hv.z = siluf(hacc[2][jj]);
            hv.w = siluf(hacc[3][jj]);
            *(float4*)&hT[(jg * 8 + jj) * 64 + eg * 4] = hv;
        }
    }
    __syncthreads();

    {
        const int eg = tid >> 4;
        const int tg = tid & 15;
        float acc[4][4];
#pragma unroll
        for (int ee = 0; ee < 4; ++ee)
#pragma unroll
            for (int tt = 0; tt < 4; ++tt) acc[ee][tt] = 0.f;
#pragma unroll 4
        for (int j = 0; j < 128; ++j) {
            float4 wv = *(const float4*)&w2[j * 64 + tg * 4];
            float4 hv = *(const float4*)&hT[j * 64 + eg * 4];
            float h[4] = {hv.x, hv.y, hv.z, hv.w};
#pragma unroll
            for (int ee = 0; ee < 4; ++ee) {
                acc[ee][0] += h[ee] * wv.x;
                acc[ee][1] += h[ee] * wv.y;
                acc[ee][2] += h[ee] * wv.z;
                acc[ee][3] += h[ee] * wv.w;
            }
        }
#pragma unroll
        for (int ee = 0; ee < 4; ++ee) {
            int e = base + eg * 4 + ee;
            if (e < E) {
                float envv = envS[eg * 4 + ee];
                float4 o;
                o.x = acc[ee][0] * envv;
                o.y = acc[ee][1] * envv;
                o.z = acc[ee][2] * envv;
                o.w = acc[ee][3] * envv;
                *(float4*)&radg[(size_t)e * 64 + tg * 4] = o;
            }
        }
    }
}

// ---------------------------------------------------------------------------
// Wigner entry (reference quirk: center z-rot element = 0)
// ---------------------------------------------------------------------------
__device__ __forceinline__ float wig_entry(int l, int i, int j, float bA, float cA,
                                           const float* __restrict__ J, int n)
{
    if (i == l) return 0.f;
    const int j2 = 2 * l - j;
    float Pij = 0.f, Pij2 = 0.f;
    for (int k = 0; k < n; ++k) {
        float sbk, cbk;
        __sincosf((float)(l - k) * bA, &sbk, &cbk);
        if (k == l) cbk = 0.f;
        float zj  = cbk * J[k * n + j]  + sbk * J[(2 * l - k) * n + j];
        float zj2 = cbk * J[k * n + j2] + sbk * J[(2 * l - k) * n + j2];
        Pij  += J[i * n + k] * zj;
        Pij2 += J[i * n + k] * zj2;
    }
    float s_, c_;
    __sincosf((float)(l - j) * cA, &s_, &c_);
    float czj = (j == l) ? 0.f : c_;
    float szj = -s_;
    return Pij * czj + Pij2 * szj;
}

// ---------------------------------------------------------------------------
// Per-edge: compute the 20 live Q = W^T W coefficients -> Qe[e][20]
//   [0..3]  = Q1 (0,0),(0,2),(2,0),(2,2)
//   [4..19] = Q2 rows{0,1,3,4} x cols{0,1,3,4}, row-major
// 4 edges per block (one wave each).
// ---------------------------------------------------------------------------
__global__ __launch_bounds__(256) void k_wig(const float* __restrict__ evec,
                                             const float* __restrict__ Jc,
                                             float* __restrict__ Qe, int E)
{
    __shared__ float sW2[4][25];
    __shared__ float sW1[4][9];
    const int w = threadIdx.x >> 6;
    const int lane = threadIdx.x & 63;
    const int e = blockIdx.x * 4 + w;
    float bA = 0.f, cA = 0.f;
    if (e < E) {
        float vx = evec[(size_t)e * 3 + 0];
        float vy = evec[(size_t)e * 3 + 1];
        float vz = evec[(size_t)e * 3 + 2];
        float dist = sqrtf(vx * vx + vy * vy + vz * vz);
        float inv = 1.0f / fmaxf(dist, 1e-7f);
        float xn = fminf(fmaxf(vx * inv, -1.f), 1.f);
        float yn = fminf(fmaxf(vy * inv, -1.f), 1.f);
        float zn = fminf(fmaxf(vz * inv, -1.f), 1.f);
        float beta = acosf(fminf(fmaxf(yn, -1.f + 1e-7f), 1.f - 1e-7f));
        float alpha = atan2f(xn, zn);
        bA = -beta;
        cA = -alpha;
    }
    if (lane < 25) {
        sW2[w][lane] = wig_entry(2, lane / 5, lane % 5, bA, cA, Jc + 9, 5);
    } else if (lane >= 32 && lane < 41) {
        int u = lane - 32;
        sW1[w][u] = wig_entry(1, u / 3, u % 3, bA, cA, Jc, 3);
    }
    __syncthreads();
    if (e < E) {
        if (lane < 16) {
            const int map[4] = {0, 1, 3, 4};
            int i = map[lane >> 2], j = map[lane & 3];
            float q = 0.f;
#pragma unroll
            for (int k = 0; k < 5; ++k) q += sW2[w][k * 5 + i] * sW2[w][k * 5 + j];
            Qe[(size_t)e * 20 + 4 + lane] = q;
        } else if (lane >= 32 && lane < 36) {
            int u = lane - 32;
            int i = (u >> 1) * 2, j = (u & 1) * 2;
            float q = 0.f;
#pragma unroll
            for (int k = 0; k < 3; ++k) q += sW1[w][k * 3 + i] * sW1[w][k * 3 + j];
            Qe[(size_t)e * 20 + u] = q;
        }
    }
}

// ---------------------------------------------------------------------------
// Counting sort by dst: histogram, scan, scatter
// ---------------------------------------------------------------------------
__global__ __launch_bounds__(256) void k_hist(const int* __restrict__ eidx,
                                              int* __restrict__ counts, int E)
{
    int e = blockIdx.x * 256 + threadIdx.x;
    if (e < E) atomicAdd(&counts[eidx[E + e]], 1);
}

__global__ __launch_bounds__(1024) void k_scan(const int* __restrict__ counts,
                                               int* __restrict__ offsets,
                                               int* __restrict__ cursors, int N)
{
    __shared__ int buf[1024];
    __shared__ int base_s;
    const int tid = threadIdx.x;
    if (tid == 0) base_s = 0;
    __syncthreads();
    for (int c0 = 0; c0 < N; c0 += 1024) {
        int i = c0 + tid;
        int v = (i < N) ? counts[i] : 0;
        buf[tid] = v;
        __syncthreads();
        for (int off = 1; off < 1024; off <<= 1) {
            int t = (tid >= off) ? buf[tid - off] : 0;
            __syncthreads();
            buf[tid] += t;
            __syncthreads();
        }
        int excl = buf[tid] - v;
        int tot = buf[1023];
        if (i < N) {
            offsets[i] = base_s + excl;
            cursors[i] = base_s + excl;
        }
        __syncthreads();
        if (tid == 0) base_s += tot;
        __syncthreads();
    }
    if (tid == 0) offsets[N] = base_s;
}

__global__ __launch_bounds__(256) void k_scatter(const int* __restrict__ eidx,
                                                 int* __restrict__ cursors,
                                                 int* __restrict__ perm, int E)
{
    int e = blockIdx.x * 256 + threadIdx.x;
    if (e < E) {
        int pos = atomicAdd(&cursors[eidx[E + e]], 1);
        perm[pos] = e;
    }
}

// ---------------------------------------------------------------------------
// Per-dst-node gather + accumulate in registers + fused M2/RMS/gamma finalize.
// No atomics, overwrites all of d_out.
// ---------------------------------------------------------------------------
__global__ __launch_bounds__(64) void k_gather_fin(const int* __restrict__ eidx,
                                                   const int* __restrict__ offsets,
                                                   const int* __restrict__ perm,
                                                   const float* __restrict__ Qe,
                                                   const float* __restrict__ radg,
                                                   const float* __restrict__ xm6,
                                                   const float* __restrict__ m2,
                                                   const float* __restrict__ gam,
                                                   float* __restrict__ out, int E)
{
    const int n = blockIdx.x;
    const int t = threadIdx.x;
    const int start = offsets[n];
    const int end = offsets[n + 1];

    float a1 = 0.f, a3 = 0.f, a4 = 0.f, a5 = 0.f, a7 = 0.f, a8 = 0.f;
    for (int i = start; i < end; ++i) {
        const int e = perm[i];
        const int src = eidx[e];
        const float* q = Qe + (size_t)e * 20;
        float4 q0 = *(const float4*)&q[0];
        float4 q1 = *(const float4*)&q[4];
        float4 q2 = *(const float4*)&q[8];
        float4 q3 = *(const float4*)&q[12];
        float4 q4 = *(const float4*)&q[16];
        const float rad = radg[(size_t)e * 64 + t];
        const float* xs = xm6 + (size_t)src * 384;
        float x1 = xs[0 * 64 + t];
        float x3 = xs[1 * 64 + t];
        float x4 = xs[2 * 64 + t];
        float x5 = xs[3 * 64 + t];
        float x7 = xs[4 * 64 + t];
        float x8 = xs[5 * 64 + t];
        a1 += rad * (q0.x * x1 + q0.y * x3);
        a3 += rad * (q0.z * x1 + q0.w * x3);
        a4 += rad * (q1.x * x4 + q1.y * x5 + q1.z * x7 + q1.w * x8);
        a5 += rad * (q2.x * x4 + q2.y * x5 + q2.z * x7 + q2.w * x8);
        a7 += rad * (q3.x * x4 + q3.y * x5 + q3.z * x7 + q3.w * x8);
        a8 += rad * (q4.x * x4 + q4.y * x5 + q4.z * x7 + q4.w * x8);
    }

    __shared__ float sa[6 * 64];
    sa[0 * 64 + t] = a1;
    sa[1 * 64 + t] = a3;
    sa[2 * 64 + t] = a4;
    sa[3 * 64 + t] = a5;
    sa[4 * 64 + t] = a7;
    sa[5 * 64 + t] = a8;
    __syncthreads();
    float v0 = 0.f, v1 = 0.f, v2 = 0.f, v3 = 0.f, v4 = 0.f, v5 = 0.f;
    for (int c = 0; c < 64; ++c) {
        float m = m2[c * 64 + t];
        v0 += sa[0 * 64 + c] * m;
        v1 += sa[1 * 64 + c] * m;
        v2 += sa[2 * 64 + c] * m;
        v3 += sa[3 * 64 + c] * m;
        v4 += sa[4 * 64 + c] * m;
        v5 += sa[5 * 64 + c] * m;
    }
    float ss = v0 * v0 + v1 * v1 + v2 * v2 + v3 * v3 + v4 * v4 + v5 * v5;
    float rms = sqrtf(ss * (1.0f / 9.0f) + 1e-7f);
    float sc = gam[t] / rms;
    float* op = out + (size_t)n * 576;
    op[0 * 64 + t] = 0.f;
    op[2 * 64 + t] = 0.f;
    op[6 * 64 + t] = 0.f;
    op[1 * 64 + t] = v0 * sc;
    op[3 * 64 + t] = v1 * sc;
    op[4 * 64 + t] = v2 * sc;
    op[5 * 64 + t] = v3 * sc;
    op[7 * 64 + t] = v4 * sc;
    op[8 * 64 + t] = v5 * sc;
}

// ---------------------------------------------------------------------------
// Legacy fallback: atomic-scatter edge kernel + separate finalize
// ---------------------------------------------------------------------------
__global__ __launch_bounds__(64) void k_edge2(const float* __restrict__ evec,
                                              const int* __restrict__ eidx,
                                              const float* __restrict__ radg,
                                              const float* __restrict__ Jc,
                                              const float* __restrict__ xm6,
                                              float* __restrict__ acc, int E)
{
    const int e = blockIdx.x;
    const int t = threadIdx.x;
    __shared__ float s_W1[9], s_W2[25], s_Q1[9], s_Q2[25];

    float vx = evec[(size_t)e * 3 + 0];
    float vy = evec[(size_t)e * 3 + 1];
    float vz = evec[(size_t)e * 3 + 2];
    float dist = sqrtf(vx * vx + vy * vy + vz * vz);
    float inv = 1.0f / fmaxf(dist, 1e-7f);
    float xn = fminf(fmaxf(vx * inv, -1.f), 1.f);
    float yn = fminf(fmaxf(vy * inv, -1.f), 1.f);
    float zn = fminf(fmaxf(vz * inv, -1.f), 1.f);
    float beta = acosf(fminf(fmaxf(yn, -1.f + 1e-7f), 1.f - 1e-7f));
    float alpha = atan2f(xn, zn);
    float bA = -beta;
    float cA = -alpha;

    if (t < 25) {
        s_W2[t] = wig_entry(2, t / 5, t % 5, bA, cA, Jc + 9, 5);
    } else if (t >= 32 && t < 41) {
        int u = t - 32;
        s_W1[u] = wig_entry(1, u / 3, u % 3, bA, cA, Jc, 3);
    }
    __syncthreads();

    if (t < 25) {
        int i = t / 5, j = t % 5;
        float q = 0.f;
#pragma unroll
        for (int k = 0; k < 5; ++k) q += s_W2[k * 5 + i] * s_W2[k * 5 + j];
        s_Q2[t] = q;
    } else if (t >= 32 && t < 41) {
        int u = t - 32;
        int i = u / 3, j = u % 3;
        float q = 0.f;
#pragma unroll
        for (int k = 0; k < 3; ++k) q += s_W1[k * 3 + i] * s_W1[k * 3 + j];
        s_Q1[u] = q;
    }
    __syncthreads();

    const float rad = radg[(size_t)e * 64 + t];
    const int src = eidx[e];
    const int dst = eidx[E + e];
    const float* xs = xm6 + (size_t)src * 384;
    float x1 = xs[0 * 64 + t];
    float x3 = xs[1 * 64 + t];
    float x4 = xs[2 * 64 + t];
    float x5 = xs[3 * 64 + t];
    float x7 = xs[4 * 64 + t];
    float x8 = xs[5 * 64 + t];

    float m1v = rad * (s_Q1[0] * x1 + s_Q1[2] * x3);
    float m3v = rad * (s_Q1[6] * x1 + s_Q1[8] * x3);
    float m4v = rad * (s_Q2[0]  * x4 + s_Q2[1]  * x5 + s_Q2[3]  * x7 + s_Q2[4]  * x8);
    float m5v = rad * (s_Q2[5]  * x4 + s_Q2[6]  * x5 + s_Q2[8]  * x7 + s_Q2[9]  * x8);
    float m7v = rad * (s_Q2[15] * x4 + s_Q2[16] * x5 + s_Q2[18] * x7 + s_Q2[19] * x8);
    float m8v = rad * (s_Q2[20] * x4 + s_Q2[21] * x5 + s_Q2[23] * x7 + s_Q2[24] * x8);

    float* ad = acc + (size_t)dst * 576;
    atomicAdd(ad + 1 * 64 + t, m1v);
    atomicAdd(ad + 3 * 64 + t, m3v);
    atomicAdd(ad + 4 * 64 + t, m4v);
    atomicAdd(ad + 5 * 64 + t, m5v);
    atomicAdd(ad + 7 * 64 + t, m7v);
    atomicAdd(ad + 8 * 64 + t, m8v);
}

__global__ __launch_bounds__(64) void k_fin(const float* __restrict__ m2,
                                            const float* __restrict__ gam,
                                            float* __restrict__ out)
{
    const int n = blockIdx.x;
    const int t = threadIdx.x;
    __shared__ float sa[6 * 64];
    float* op = out + (size_t)n * 576;
    sa[0 * 64 + t] = op[1 * 64 + t];
    sa[1 * 64 + t] = op[3 * 64 + t];
    sa[2 * 64 + t] = op[4 * 64 + t];
    sa[3 * 64 + t] = op[5 * 64 + t];
    sa[4 * 64 + t] = op[7 * 64 + t];
    sa[5 * 64 + t] = op[8 * 64 + t];
    __syncthreads();
    float v0 = 0.f, v1 = 0.f, v2 = 0.f, v3 = 0.f, v4 = 0.f, v5 = 0.f;
    for (int c = 0; c < 64; ++c) {
        float m = m2[c * 64 + t];
        v0 += sa[0 * 64 + c] * m;
        v1 += sa[1 * 64 + c] * m;
        v2 += sa[2 * 64 + c] * m;
        v3 += sa[3 * 64 + c] * m;
        v4 += sa[4 * 64 + c] * m;
        v5 += sa[5 * 64 + c] * m;
    }
    float ss = v0 * v0 + v1 * v1 + v2 * v2 + v3 * v3 + v4 * v4 + v5 * v5;
    float rms = sqrtf(ss * (1.0f / 9.0f) + 1e-7f);
    float sc = gam[t] / rms;
    op[0 * 64 + t] = 0.f;
    op[2 * 64 + t] = 0.f;
    op[6 * 64 + t] = 0.f;
    op[1 * 64 + t] = v0 * sc;
    op[3 * 64 + t] = v1 * sc;
    op[4 * 64 + t] = v2 * sc;
    op[5 * 64 + t] = v3 * sc;
    op[7 * 64 + t] = v4 * sc;
    op[8 * 64 + t] = v5 * sc;
}

static inline size_t align256(size_t x) { return (x + 255) & ~(size_t)255; }

extern "C" void kernel_launch(void* const* d_in, const int* in_sizes, int n_in,
                              void* d_out, int out_size, void* d_ws, size_t ws_size,
                              hipStream_t stream)
{
    const float* nf  = (const float*)d_in[0];
    const float* ev  = (const float*)d_in[1];
    const int*   ei  = (const int*)d_in[2];
    const float* w1  = (const float*)d_in[3];
    const float* b1  = (const float*)d_in[4];
    const float* w2  = (const float*)d_in[5];
    const float* m1  = (const float*)d_in[6];
    const float* m2  = (const float*)d_in[7];
    const float* gam = (const float*)d_in[8];

    const int N = in_sizes[0] / (SPHN * CHN);
    const int E = in_sizes[1] / 3;

    float* out = (float*)d_out;
    char* base = (char*)d_ws;
    size_t off = 0;
    float* Jc = (float*)(base + off);            off += align256(34 * sizeof(float));
    float* xm6 = (float*)(base + off);           off += align256((size_t)N * 384 * sizeof(float));
    float* radg = (float*)(base + off);          off += align256((size_t)E * 64 * sizeof(float));
    size_t need_old = off;                       // through radg
    float* Qe = (float*)(base + off);            off += align256((size_t)E * 20 * sizeof(float));
    int* counts = (int*)(base + off);            off += align256((size_t)N * sizeof(int));
    int* offsets = (int*)(base + off);           off += align256((size_t)(N + 1) * sizeof(int));
    int* cursors = (int*)(base + off);           off += align256((size_t)N * sizeof(int));
    int* perm = (int*)(base + off);              off += align256((size_t)E * sizeof(int));
    size_t need_new = off;

    hipLaunchKernelGGL(k_setup_J, dim3(1), dim3(64), 0, stream, Jc);
    hipLaunchKernelGGL(k_xm, dim3(N), dim3(64), 0, stream, nf, m1, xm6);

    if (ws_size >= need_new) {
        hipLaunchKernelGGL(k_rad, dim3((E + 63) / 64), dim3(256), 0, stream,
                           ev, w1, b1, w2, radg, E);
        hipLaunchKernelGGL(k_wig, dim3((E + 3) / 4), dim3(256), 0, stream,
                           ev, Jc, Qe, E);
        hipMemsetAsync(counts, 0, (size_t)N * sizeof(int), stream);
        hipLaunchKernelGGL(k_hist, dim3((E + 255) / 256), dim3(256), 0, stream,
                           ei, counts, E);
        hipLaunchKernelGGL(k_scan, dim3(1), dim3(1024), 0, stream,
                           counts, offsets, cursors, N);
        hipLaunchKernelGGL(k_scatter, dim3((E + 255) / 256), dim3(256), 0, stream,
                           ei, cursors, perm, E);
        hipLaunchKernelGGL(k_gather_fin, dim3(N), dim3(64), 0, stream,
                           ei, offsets, perm, Qe, radg, xm6, m2, gam, out, E);
    } else if (ws_size >= need_old) {
        hipMemsetAsync(d_out, 0, (size_t)out_size * sizeof(float), stream);
        hipLaunchKernelGGL(k_rad, dim3((E + 63) / 64), dim3(256), 0, stream,
                           ev, w1, b1, w2, radg, E);
        hipLaunchKernelGGL(k_edge2, dim3(E), dim3(64), 0, stream,
                           ev, ei, radg, Jc, xm6, out, E);
        hipLaunchKernelGGL(k_fin, dim3(N), dim3(64), 0, stream, m2, gam, out);
    }
}

// Round 5
// 265.438 us; speedup vs baseline: 1.3499x; 1.0309x over previous
//
#include <hip/hip_runtime.h>

#define SPHN 9
#define CHN 64

// ---------------------------------------------------------------------------
// Setup: real Wigner J matrices (l=1: 3x3 at Jout[0..8], l=2: 5x5 at
// Jout[9..33]), double precision, exact transcription of reference.
// ---------------------------------------------------------------------------
__global__ void k_setup_J(float* __restrict__ Jout)
{
    if (blockIdx.x != 0 || threadIdx.x != 0) return;
    double fact[9];
    fact[0] = 1.0;
    for (int i = 1; i < 9; ++i) fact[i] = fact[i - 1] * (double)i;
    const double is2 = 0.70710678118654752440;
    int outoff = 0;
    for (int l = 1; l <= 2; ++l) {
        const int n = 2 * l + 1;
        double d[5][5];
        for (int mp = -l; mp <= l; ++mp)
            for (int m = -l; m <= l; ++m) {
                double val = 0.0;
                int k0 = (m - mp) > 0 ? (m - mp) : 0;
                int k1 = (l + m < l - mp) ? (l + m) : (l - mp);
                for (int k = k0; k <= k1; ++k) {
                    double sign = ((mp - m + k) & 1) ? -1.0 : 1.0;
                    double num = sign * sqrt(fact[l + mp] * fact[l - mp] * fact[l + m] * fact[l - m]);
                    double den = fact[l + m - k] * fact[k] * fact[mp - m + k] * fact[l - mp - k];
                    double cp = 1.0;
                    for (int q = 0; q < 2 * l + m - mp - 2 * k; ++q) cp *= is2;
                    double sp = 1.0;
                    for (int q = 0; q < mp - m + 2 * k; ++q) sp *= is2;
                    val += num / den * cp * sp;
                }
                d[mp + l][m + l] = val;
            }
        double Cre[5][5] = {{0}}, Cim[5][5] = {{0}};
        for (int m = -l; m <= l; ++m) {
            if (m == 0) {
                Cre[l][l] = 1.0;
            } else if (m > 0) {
                Cre[m + l][-m + l] = is2;
                Cre[m + l][m + l] = ((m & 1) ? -1.0 : 1.0) * is2;
            } else {
                Cim[m + l][m + l] = is2;
                Cim[m + l][-m + l] = -(((m & 1)) ? -1.0 : 1.0) * is2;
            }
        }
        double Tre[5][5], Tim[5][5];
        for (int i = 0; i < n; ++i)
            for (int j = 0; j < n; ++j) {
                double tr = 0.0, ti = 0.0;
                for (int k = 0; k < n; ++k) {
                    tr += d[i][k] * Cre[j][k];
                    ti -= d[i][k] * Cim[j][k];
                }
                Tre[i][j] = tr;
                Tim[i][j] = ti;
            }
        for (int i = 0; i < n; ++i)
            for (int j = 0; j < n; ++j) {
                double jr = 0.0;
                for (int k = 0; k < n; ++k)
                    jr += Cre[i][k] * Tre[k][j] - Cim[i][k] * Tim[k][j];
                Jout[outoff + i * n + j] = (float)jr;
            }
        outoff += n * n;
    }
}

// ---------------------------------------------------------------------------
// Per-node: xm = node_feats @ W_msg1, only needed SPH rows {1,3,4,5,7,8}
// ---------------------------------------------------------------------------
__global__ __launch_bounds__(64) void k_xm(const float* __restrict__ nf,
                                           const float* __restrict__ m1,
                                           float* __restrict__ xm6)
{
    const int n = blockIdx.x;
    const int t = threadIdx.x;
    __shared__ float sx[SPHN * CHN];
    const float* xp = nf + (size_t)n * (SPHN * CHN);
#pragma unroll
    for (int i = 0; i < 9; ++i) sx[i * 64 + t] = xp[i * 64 + t];
    __syncthreads();
    float a0 = 0.f, a1 = 0.f, a2 = 0.f, a3 = 0.f, a4 = 0.f, a5 = 0.f;
    for (int c = 0; c < 64; ++c) {
        float m = m1[c * 64 + t];
        a0 += sx[1 * 64 + c] * m;
        a1 += sx[3 * 64 + c] * m;
        a2 += sx[4 * 64 + c] * m;
        a3 += sx[5 * 64 + c] * m;
        a4 += sx[7 * 64 + c] * m;
        a5 += sx[8 * 64 + c] * m;
    }
    float* op = xm6 + (size_t)n * 384;
    op[0 * 64 + t] = a0;
    op[1 * 64 + t] = a1;
    op[2 * 64 + t] = a2;
    op[3 * 64 + t] = a3;
    op[4 * 64 + t] = a4;
    op[5 * 64 + t] = a5;
}

__device__ __forceinline__ float siluf(float x) { return x / (1.f + expf(-x)); }

// ---------------------------------------------------------------------------
// Radial MLP tiled GEMM: 64 edges/block, 256 threads.
// Lane mapping: eg = tid&15 (16 edge-groups), jg/tg = tid>>4 — this makes
// Phase B's hT stores cover all 32 LDS banks uniformly (was: banks 0-15
// only -> 2.8M bank-conflict cycles).
// ---------------------------------------------------------------------------
__global__ __launch_bounds__(256) void k_rad(const float* __restrict__ evec,
                                             const float* __restrict__ w1,
                                             const float* __restrict__ b1,
                                             const float* __restrict__ w2,
                                             float* __restrict__ radg,
                                             int E)
{
    __shared__ float rbfT[64 * 64];   // [k][e]
    __shared__ float hT[128 * 64];    // [j][e]
    __shared__ float distS[64];
    __shared__ float envS[64];
    const int tid = threadIdx.x;
    const int base = blockIdx.x * 64;

    if (tid < 64) {
        int e = base + tid;
        float dist = 0.f;
        if (e < E) {
            float vx = evec[(size_t)e * 3 + 0];
            float vy = evec[(size_t)e * 3 + 1];
            float vz = evec[(size_t)e * 3 + 2];
            dist = sqrtf(vx * vx + vy * vy + vz * vz);
        }
        distS[tid] = dist;
        float dd = dist * (1.0f / 6.0f);
        float env = 0.f;
        if (dd < 1.0f) {
            float d2 = dd * dd;
            float d5 = d2 * d2 * dd;
            env = 1.0f - 21.0f * d5 + 35.0f * d5 * dd - 15.0f * d5 * d2;
        }
        envS[tid] = env;
    }
    __syncthreads();
    const float step = 6.0f / 63.0f;
#pragma unroll
    for (int p = 0; p < 16; ++p) {
        int idx = p * 256 + tid;
        int k = idx >> 6, e = idx & 63;
        float diff = distS[e] - step * (float)k;
        rbfT[idx] = expf(-55.125f * diff * diff);
    }
    __syncthreads();

    // Phase B: h = silu(rbf @ W1 + b1) -> hT[j][e]
    {
        const int eg = tid & 15;        // 16 edge-groups of 4
        const int jg = tid >> 4;        // 16 j-groups of 8
        float hacc[4][8];
        float4 b0 = *(const float4*)&b1[jg * 8];
        float4 b4 = *(const float4*)&b1[jg * 8 + 4];
#pragma unroll
        for (int ee = 0; ee < 4; ++ee) {
            hacc[ee][0] = b0.x; hacc[ee][1] = b0.y; hacc[ee][2] = b0.z; hacc[ee][3] = b0.w;
            hacc[ee][4] = b4.x; hacc[ee][5] = b4.y; hacc[ee][6] = b4.z; hacc[ee][7] = b4.w;
        }
#pragma unroll 4
        for (int k = 0; k < 64; ++k) {
            float4 wa = *(const float4*)&w1[k * 128 + jg * 8];
            float4 wb = *(const float4*)&w1[k * 128 + jg * 8 + 4];
            float4 rb = *(const float4*)&rbfT[k * 64 + eg * 4];
            float r[4] = {rb.x, rb.y, rb.z, rb.w};
#pragma unroll
            for (int ee = 0; ee < 4; ++ee) {
                hacc[ee][0] += r[ee] * wa.x;
                hacc[ee][1] += r[ee] * wa.y;
                hacc[ee][2] += r[ee] * wa.z;
                hacc[ee][3] += r[ee] * wa.w;
                hacc[ee][4] += r[ee] * wb.x;
                hacc[ee][5] += r[ee] * wb.y;
                hacc[ee][6] += r[ee] * wb.z;
                hacc[ee][7] += r[ee] * wb.w;
            }
        }
#pragma unroll
        for (int jj = 0; jj < 8; ++jj) {
            float4 hv;
            hv.x = siluf(hacc[0][jj]);
            hv.y = siluf(hacc[1][jj]);
            hv.z = siluf(hacc[2][jj]);
            hv.w = siluf(hacc[3][jj]);
            *(float4*)&hT[(jg * 8 + jj) * 64 + eg * 4] = hv;
        }
    }
    __syncthreads();

    // Phase C: rad = h @ W2 * env  (hT reads are 4-addr broadcast: free)
    {
        const int eg = tid >> 4;
        const int tg = tid & 15;
        float acc[4][4];
#pragma unroll
        for (int ee = 0; ee < 4; ++ee)
#pragma unroll
            for (int tt = 0; tt < 4; ++tt) acc[ee][tt] = 0.f;
#pragma unroll 4
        for (int j = 0; j < 128; ++j) {
            float4 wv = *(const float4*)&w2[j * 64 + tg * 4];
            float4 hv = *(const float4*)&hT[j * 64 + eg * 4];
            float h[4] = {hv.x, hv.y, hv.z, hv.w};
#pragma unroll
            for (int ee = 0; ee < 4; ++ee) {
                acc[ee][0] += h[ee] * wv.x;
                acc[ee][1] += h[ee] * wv.y;
                acc[ee][2] += h[ee] * wv.z;
                acc[ee][3] += h[ee] * wv.w;
            }
        }
#pragma unroll
        for (int ee = 0; ee < 4; ++ee) {
            int e = base + eg * 4 + ee;
            if (e < E) {
                float envv = envS[eg * 4 + ee];
                float4 o;
                o.x = acc[ee][0] * envv;
                o.y = acc[ee][1] * envv;
                o.z = acc[ee][2] * envv;
                o.w = acc[ee][3] * envv;
                *(float4*)&radg[(size_t)e * 64 + tg * 4] = o;
            }
        }
    }
}

// ---------------------------------------------------------------------------
// Wigner entry (reference quirk: center z-rot element = 0)
// ---------------------------------------------------------------------------
__device__ __forceinline__ float wig_entry(int l, int i, int j, float bA, float cA,
                                           const float* __restrict__ J, int n)
{
    if (i == l) return 0.f;
    const int j2 = 2 * l - j;
    float Pij = 0.f, Pij2 = 0.f;
    for (int k = 0; k < n; ++k) {
        float sbk, cbk;
        __sincosf((float)(l - k) * bA, &sbk, &cbk);
        if (k == l) cbk = 0.f;
        float zj  = cbk * J[k * n + j]  + sbk * J[(2 * l - k) * n + j];
        float zj2 = cbk * J[k * n + j2] + sbk * J[(2 * l - k) * n + j2];
        Pij  += J[i * n + k] * zj;
        Pij2 += J[i * n + k] * zj2;
    }
    float s_, c_;
    __sincosf((float)(l - j) * cA, &s_, &c_);
    float czj = (j == l) ? 0.f : c_;
    float szj = -s_;
    return Pij * czj + Pij2 * szj;
}

// ---------------------------------------------------------------------------
// Per-edge: 20 live Q = W^T W coefficients -> Qe[e][20]; also dst histogram
// (k_hist folded in: lane 0 of each wave).
// ---------------------------------------------------------------------------
__global__ __launch_bounds__(256) void k_wig(const float* __restrict__ evec,
                                             const int* __restrict__ eidx,
                                             const float* __restrict__ Jc,
                                             float* __restrict__ Qe,
                                             int* __restrict__ counts, int E)
{
    __shared__ float sW2[4][25];
    __shared__ float sW1[4][9];
    const int w = threadIdx.x >> 6;
    const int lane = threadIdx.x & 63;
    const int e = blockIdx.x * 4 + w;
    float bA = 0.f, cA = 0.f;
    if (e < E) {
        float vx = evec[(size_t)e * 3 + 0];
        float vy = evec[(size_t)e * 3 + 1];
        float vz = evec[(size_t)e * 3 + 2];
        float dist = sqrtf(vx * vx + vy * vy + vz * vz);
        float inv = 1.0f / fmaxf(dist, 1e-7f);
        float xn = fminf(fmaxf(vx * inv, -1.f), 1.f);
        float yn = fminf(fmaxf(vy * inv, -1.f), 1.f);
        float zn = fminf(fmaxf(vz * inv, -1.f), 1.f);
        float beta = acosf(fminf(fmaxf(yn, -1.f + 1e-7f), 1.f - 1e-7f));
        float alpha = atan2f(xn, zn);
        bA = -beta;
        cA = -alpha;
        if (lane == 0) atomicAdd(&counts[eidx[E + e]], 1);
    }
    if (lane < 25) {
        sW2[w][lane] = wig_entry(2, lane / 5, lane % 5, bA, cA, Jc + 9, 5);
    } else if (lane >= 32 && lane < 41) {
        int u = lane - 32;
        sW1[w][u] = wig_entry(1, u / 3, u % 3, bA, cA, Jc, 3);
    }
    __syncthreads();
    if (e < E) {
        if (lane < 16) {
            const int map[4] = {0, 1, 3, 4};
            int i = map[lane >> 2], j = map[lane & 3];
            float q = 0.f;
#pragma unroll
            for (int k = 0; k < 5; ++k) q += sW2[w][k * 5 + i] * sW2[w][k * 5 + j];
            Qe[(size_t)e * 20 + 4 + lane] = q;
        } else if (lane >= 32 && lane < 36) {
            int u = lane - 32;
            int i = (u >> 1) * 2, j = (u & 1) * 2;
            float q = 0.f;
#pragma unroll
            for (int k = 0; k < 3; ++k) q += sW1[w][k * 3 + i] * sW1[w][k * 3 + j];
            Qe[(size_t)e * 20 + u] = q;
        }
    }
}

// ---------------------------------------------------------------------------
// Exclusive scan of counts[N] -> offsets/cursors, offsets[N]=total.
// Single block, 1024 threads, shuffle-based (3 barriers, two passes over
// counts instead of a 100-barrier Hillis-Steele).
// ---------------------------------------------------------------------------
__global__ __launch_bounds__(1024) void k_scan(const int* __restrict__ counts,
                                               int* __restrict__ offsets,
                                               int* __restrict__ cursors, int N)
{
    __shared__ int wsum[16];
    __shared__ int wpre[16];
    const int tid = threadIdx.x;
    const int lane = tid & 63;
    const int wid = tid >> 6;
    const int per = (N + 1023) >> 10;
    const int begin = tid * per;
    const int endi = (begin + per < N) ? (begin + per) : N;

    int s = 0;
    for (int i = begin; i < endi; ++i) s += counts[i];

    int inc = s;
#pragma unroll
    for (int off = 1; off < 64; off <<= 1) {
        int u = __shfl_up(inc, off, 64);
        if (lane >= off) inc += u;
    }
    if (lane == 63) wsum[wid] = inc;
    __syncthreads();
    if (wid == 0) {
        int v = (lane < 16) ? wsum[lane] : 0;
        int winc = v;
#pragma unroll
        for (int off = 1; off < 16; off <<= 1) {
            int u = __shfl_up(winc, off, 64);
            if (lane >= off) winc += u;
        }
        if (lane < 16) wpre[lane] = winc - v;
    }
    __syncthreads();
    int run = wpre[wid] + (inc - s);
    for (int i = begin; i < endi; ++i) {
        int c = counts[i];
        offsets[i] = run;
        cursors[i] = run;
        run += c;
    }
    if (endi == N && begin < N) offsets[N] = run;
}

__global__ __launch_bounds__(256) void k_scatter(const int* __restrict__ eidx,
                                                 int* __restrict__ cursors,
                                                 int* __restrict__ perm, int E)
{
    int e = blockIdx.x * 256 + threadIdx.x;
    if (e < E) {
        int pos = atomicAdd(&cursors[eidx[E + e]], 1);
        perm[pos] = e;
    }
}

// ---------------------------------------------------------------------------
// Per-dst-node gather + register accumulate + fused M2/RMS/gamma finalize.
// ---------------------------------------------------------------------------
__global__ __launch_bounds__(64) void k_gather_fin(const int* __restrict__ eidx,
                                                   const int* __restrict__ offsets,
                                                   const int* __restrict__ perm,
                                                   const float* __restrict__ Qe,
                                                   const float* __restrict__ radg,
                                                   const float* __restrict__ xm6,
                                                   const float* __restrict__ m2,
                                                   const float* __restrict__ gam,
                                                   float* __restrict__ out, int E)
{
    const int n = blockIdx.x;
    const int t = threadIdx.x;
    const int start = offsets[n];
    const int end = offsets[n + 1];

    float a1 = 0.f, a3 = 0.f, a4 = 0.f, a5 = 0.f, a7 = 0.f, a8 = 0.f;
    for (int i = start; i < end; ++i) {
        const int e = perm[i];
        const int src = eidx[e];
        const float* q = Qe + (size_t)e * 20;
        float4 q0 = *(const float4*)&q[0];
        float4 q1 = *(const float4*)&q[4];
        float4 q2 = *(const float4*)&q[8];
        float4 q3 = *(const float4*)&q[12];
        float4 q4 = *(const float4*)&q[16];
        const float rad = radg[(size_t)e * 64 + t];
        const float* xs = xm6 + (size_t)src * 384;
        float x1 = xs[0 * 64 + t];
        float x3 = xs[1 * 64 + t];
        float x4 = xs[2 * 64 + t];
        float x5 = xs[3 * 64 + t];
        float x7 = xs[4 * 64 + t];
        float x8 = xs[5 * 64 + t];
        a1 += rad * (q0.x * x1 + q0.y * x3);
        a3 += rad * (q0.z * x1 + q0.w * x3);
        a4 += rad * (q1.x * x4 + q1.y * x5 + q1.z * x7 + q1.w * x8);
        a5 += rad * (q2.x * x4 + q2.y * x5 + q2.z * x7 + q2.w * x8);
        a7 += rad * (q3.x * x4 + q3.y * x5 + q3.z * x7 + q3.w * x8);
        a8 += rad * (q4.x * x4 + q4.y * x5 + q4.z * x7 + q4.w * x8);
    }

    __shared__ float sa[6 * 64];
    sa[0 * 64 + t] = a1;
    sa[1 * 64 + t] = a3;
    sa[2 * 64 + t] = a4;
    sa[3 * 64 + t] = a5;
    sa[4 * 64 + t] = a7;
    sa[5 * 64 + t] = a8;
    __syncthreads();
    float v0 = 0.f, v1 = 0.f, v2 = 0.f, v3 = 0.f, v4 = 0.f, v5 = 0.f;
    for (int c = 0; c < 64; ++c) {
        float m = m2[c * 64 + t];
        v0 += sa[0 * 64 + c] * m;
        v1 += sa[1 * 64 + c] * m;
        v2 += sa[2 * 64 + c] * m;
        v3 += sa[3 * 64 + c] * m;
        v4 += sa[4 * 64 + c] * m;
        v5 += sa[5 * 64 + c] * m;
    }
    float ss = v0 * v0 + v1 * v1 + v2 * v2 + v3 * v3 + v4 * v4 + v5 * v5;
    float rms = sqrtf(ss * (1.0f / 9.0f) + 1e-7f);
    float sc = gam[t] / rms;
    float* op = out + (size_t)n * 576;
    op[0 * 64 + t] = 0.f;
    op[2 * 64 + t] = 0.f;
    op[6 * 64 + t] = 0.f;
    op[1 * 64 + t] = v0 * sc;
    op[3 * 64 + t] = v1 * sc;
    op[4 * 64 + t] = v2 * sc;
    op[5 * 64 + t] = v3 * sc;
    op[7 * 64 + t] = v4 * sc;
    op[8 * 64 + t] = v5 * sc;
}

// ---------------------------------------------------------------------------
// Legacy fallback path (small ws): atomic scatter + separate finalize
// ---------------------------------------------------------------------------
__global__ __launch_bounds__(64) void k_edge2(const float* __restrict__ evec,
                                              const int* __restrict__ eidx,
                                              const float* __restrict__ radg,
                                              const float* __restrict__ Jc,
                                              const float* __restrict__ xm6,
                                              float* __restrict__ acc, int E)
{
    const int e = blockIdx.x;
    const int t = threadIdx.x;
    __shared__ float s_W1[9], s_W2[25], s_Q1[9], s_Q2[25];

    float vx = evec[(size_t)e * 3 + 0];
    float vy = evec[(size_t)e * 3 + 1];
    float vz = evec[(size_t)e * 3 + 2];
    float dist = sqrtf(vx * vx + vy * vy + vz * vz);
    float inv = 1.0f / fmaxf(dist, 1e-7f);
    float xn = fminf(fmaxf(vx * inv, -1.f), 1.f);
    float yn = fminf(fmaxf(vy * inv, -1.f), 1.f);
    float zn = fminf(fmaxf(vz * inv, -1.f), 1.f);
    float beta = acosf(fminf(fmaxf(yn, -1.f + 1e-7f), 1.f - 1e-7f));
    float alpha = atan2f(xn, zn);
    float bA = -beta;
    float cA = -alpha;

    if (t < 25) {
        s_W2[t] = wig_entry(2, t / 5, t % 5, bA, cA, Jc + 9, 5);
    } else if (t >= 32 && t < 41) {
        int u = t - 32;
        s_W1[u] = wig_entry(1, u / 3, u % 3, bA, cA, Jc, 3);
    }
    __syncthreads();

    if (t < 25) {
        int i = t / 5, j = t % 5;
        float q = 0.f;
#pragma unroll
        for (int k = 0; k < 5; ++k) q += s_W2[k * 5 + i] * s_W2[k * 5 + j];
        s_Q2[t] = q;
    } else if (t >= 32 && t < 41) {
        int u = t - 32;
        int i = u / 3, j = u % 3;
        float q = 0.f;
#pragma unroll
        for (int k = 0; k < 3; ++k) q += s_W1[k * 3 + i] * s_W1[k * 3 + j];
        s_Q1[u] = q;
    }
    __syncthreads();

    const float rad = radg[(size_t)e * 64 + t];
    const int src = eidx[e];
    const int dst = eidx[E + e];
    const float* xs = xm6 + (size_t)src * 384;
    float x1 = xs[0 * 64 + t];
    float x3 = xs[1 * 64 + t];
    float x4 = xs[2 * 64 + t];
    float x5 = xs[3 * 64 + t];
    float x7 = xs[4 * 64 + t];
    float x8 = xs[5 * 64 + t];

    float m1v = rad * (s_Q1[0] * x1 + s_Q1[2] * x3);
    float m3v = rad * (s_Q1[6] * x1 + s_Q1[8] * x3);
    float m4v = rad * (s_Q2[0]  * x4 + s_Q2[1]  * x5 + s_Q2[3]  * x7 + s_Q2[4]  * x8);
    float m5v = rad * (s_Q2[5]  * x4 + s_Q2[6]  * x5 + s_Q2[8]  * x7 + s_Q2[9]  * x8);
    float m7v = rad * (s_Q2[15] * x4 + s_Q2[16] * x5 + s_Q2[18] * x7 + s_Q2[19] * x8);
    float m8v = rad * (s_Q2[20] * x4 + s_Q2[21] * x5 + s_Q2[23] * x7 + s_Q2[24] * x8);

    float* ad = acc + (size_t)dst * 576;
    atomicAdd(ad + 1 * 64 + t, m1v);
    atomicAdd(ad + 3 * 64 + t, m3v);
    atomicAdd(ad + 4 * 64 + t, m4v);
    atomicAdd(ad + 5 * 64 + t, m5v);
    atomicAdd(ad + 7 * 64 + t, m7v);
    atomicAdd(ad + 8 * 64 + t, m8v);
}

__global__ __launch_bounds__(64) void k_fin(const float* __restrict__ m2,
                                            const float* __restrict__ gam,
                                            float* __restrict__ out)
{
    const int n = blockIdx.x;
    const int t = threadIdx.x;
    __shared__ float sa[6 * 64];
    float* op = out + (size_t)n * 576;
    sa[0 * 64 + t] = op[1 * 64 + t];
    sa[1 * 64 + t] = op[3 * 64 + t];
    sa[2 * 64 + t] = op[4 * 64 + t];
    sa[3 * 64 + t] = op[5 * 64 + t];
    sa[4 * 64 + t] = op[7 * 64 + t];
    sa[5 * 64 + t] = op[8 * 64 + t];
    __syncthreads();
    float v0 = 0.f, v1 = 0.f, v2 = 0.f, v3 = 0.f, v4 = 0.f, v5 = 0.f;
    for (int c = 0; c < 64; ++c) {
        float m = m2[c * 64 + t];
        v0 += sa[0 * 64 + c] * m;
        v1 += sa[1 * 64 + c] * m;
        v2 += sa[2 * 64 + c] * m;
        v3 += sa[3 * 64 + c] * m;
        v4 += sa[4 * 64 + c] * m;
        v5 += sa[5 * 64 + c] * m;
    }
    float ss = v0 * v0 + v1 * v1 + v2 * v2 + v3 * v3 + v4 * v4 + v5 * v5;
    float rms = sqrtf(ss * (1.0f / 9.0f) + 1e-7f);
    float sc = gam[t] / rms;
    op[0 * 64 + t] = 0.f;
    op[2 * 64 + t] = 0.f;
    op[6 * 64 + t] = 0.f;
    op[1 * 64 + t] = v0 * sc;
    op[3 * 64 + t] = v1 * sc;
    op[4 * 64 + t] = v2 * sc;
    op[5 * 64 + t] = v3 * sc;
    op[7 * 64 + t] = v4 * sc;
    op[8 * 64 + t] = v5 * sc;
}

static inline size_t align256(size_t x) { return (x + 255) & ~(size_t)255; }

extern "C" void kernel_launch(void* const* d_in, const int* in_sizes, int n_in,
                              void* d_out, int out_size, void* d_ws, size_t ws_size,
                              hipStream_t stream)
{
    const float* nf  = (const float*)d_in[0];
    const float* ev  = (const float*)d_in[1];
    const int*   ei  = (const int*)d_in[2];
    const float* w1  = (const float*)d_in[3];
    const float* b1  = (const float*)d_in[4];
    const float* w2  = (const float*)d_in[5];
    const float* m1  = (const float*)d_in[6];
    const float* m2  = (const float*)d_in[7];
    const float* gam = (const float*)d_in[8];

    const int N = in_sizes[0] / (SPHN * CHN);
    const int E = in_sizes[1] / 3;

    float* out = (float*)d_out;
    char* base = (char*)d_ws;
    size_t off = 0;
    float* Jc = (float*)(base + off);            off += align256(34 * sizeof(float));
    float* xm6 = (float*)(base + off);           off += align256((size_t)N * 384 * sizeof(float));
    float* radg = (float*)(base + off);          off += align256((size_t)E * 64 * sizeof(float));
    size_t need_old = off;                       // through radg
    float* Qe = (float*)(base + off);            off += align256((size_t)E * 20 * sizeof(float));
    int* counts = (int*)(base + off);            off += align256((size_t)N * sizeof(int));
    int* offsets = (int*)(base + off);           off += align256((size_t)(N + 1) * sizeof(int));
    int* cursors = (int*)(base + off);           off += align256((size_t)N * sizeof(int));
    int* perm = (int*)(base + off);              off += align256((size_t)E * sizeof(int));
    size_t need_new = off;

    hipLaunchKernelGGL(k_setup_J, dim3(1), dim3(64), 0, stream, Jc);
    hipLaunchKernelGGL(k_xm, dim3(N), dim3(64), 0, stream, nf, m1, xm6);

    if (ws_size >= need_new) {
        hipMemsetAsync(counts, 0, (size_t)N * sizeof(int), stream);
        hipLaunchKernelGGL(k_rad, dim3((E + 63) / 64), dim3(256), 0, stream,
                           ev, w1, b1, w2, radg, E);
        hipLaunchKernelGGL(k_wig, dim3((E + 3) / 4), dim3(256), 0, stream,
                           ev, ei, Jc, Qe, counts, E);
        hipLaunchKernelGGL(k_scan, dim3(1), dim3(1024), 0, stream,
                           counts, offsets, cursors, N);
        hipLaunchKernelGGL(k_scatter, dim3((E + 255) / 256), dim3(256), 0, stream,
                           ei, cursors, perm, E);
        hipLaunchKernelGGL(k_gather_fin, dim3(N), dim3(64), 0, stream,
                           ei, offsets, perm, Qe, radg, xm6, m2, gam, out, E);
    } else if (ws_size >= need_old) {
        hipMemsetAsync(d_out, 0, (size_t)out_size * sizeof(float), stream);
        hipLaunchKernelGGL(k_rad, dim3((E + 63) / 64), dim3(256), 0, stream,
                           ev, w1, b1, w2, radg, E);
        hipLaunchKernelGGL(k_edge2, dim3(E), dim3(64), 0, stream,
                           ev, ei, radg, Jc, xm6, out, E);
        hipLaunchKernelGGL(k_fin, dim3(N), dim3(64), 0, stream, m2, gam, out);
    }
}

// Round 6
// 235.756 us; speedup vs baseline: 1.5199x; 1.1259x over previous
//
#include <hip/hip_runtime.h>

#define SPHN 9
#define CHN 64

// ---------------------------------------------------------------------------
// Setup: parallel Wigner-J build (l=1 -> Jout[0..8], l=2 -> Jout[9..33]) in
// double precision (exact reference transcription), PLUS zeroing of counts[N]
// across the whole grid (replaces a separate memset launch).
// ---------------------------------------------------------------------------
__device__ __forceinline__ void centry(int l, int r, int c, double& re, double& im)
{
    const double is2 = 0.70710678118654752440;
    re = 0.0; im = 0.0;
    int m = r - l;
    if (m == 0) {
        if (c == l) re = 1.0;
    } else if (m > 0) {
        if (c == l - m) re = is2;
        else if (c == l + m) re = (m & 1) ? -is2 : is2;
    } else {
        if (c == l + m) im = is2;
        else if (c == l - m) im = (m & 1) ? is2 : -is2;
    }
}

__global__ __launch_bounds__(256) void k_setup(float* __restrict__ Jout,
                                               int* __restrict__ counts, int N)
{
    int gid = blockIdx.x * 256 + threadIdx.x;
    if (counts != nullptr && gid < N) counts[gid] = 0;
    if (blockIdx.x != 0) return;

    const int tid = threadIdx.x;
    __shared__ double factS[9];
    __shared__ double dS[34];
    if (tid < 9) {
        double f = 1.0;
        for (int q = 2; q <= tid; ++q) f *= (double)q;
        factS[tid] = f;
    }
    __syncthreads();

    int l = 0, i = 0, j = 0, base = 0, n = 0;
    bool active = false;
    if (tid < 9)       { l = 1; n = 3; base = 0; i = tid / 3;       j = tid % 3;       active = true; }
    else if (tid < 34) { l = 2; n = 5; base = 9; i = (tid - 9) / 5; j = (tid - 9) % 5; active = true; }

    if (active) {
        const double is2 = 0.70710678118654752440;
        int mp = i - l, m = j - l;
        double val = 0.0;
        int k0 = (m - mp) > 0 ? (m - mp) : 0;
        int k1 = (l + m < l - mp) ? (l + m) : (l - mp);
        for (int k = k0; k <= k1; ++k) {
            double sign = ((mp - m + k) & 1) ? -1.0 : 1.0;
            double num = sign * sqrt(factS[l + mp] * factS[l - mp] * factS[l + m] * factS[l - m]);
            double den = factS[l + m - k] * factS[k] * factS[mp - m + k] * factS[l - mp - k];
            double cp = 1.0;
            for (int q = 0; q < 2 * l + m - mp - 2 * k; ++q) cp *= is2;
            double sp = 1.0;
            for (int q = 0; q < mp - m + 2 * k; ++q) sp *= is2;
            val += num / den * cp * sp;
        }
        dS[base + i * n + j] = val;
    }
    __syncthreads();

    if (active) {
        // J[i][j] = Re( sum_{k in {i, n1-i}} C[i][k] * T[k] ),
        // T[k] = sum_{m in {j, n1-j}} d[k][m] * conj(C[j][m])
        const int n1 = n - 1;
        double jr = 0.0;
        double cjr, cji, ckr, cki;

        // T(i)
        {
            int k = i;
            centry(l, j, j, cjr, cji);
            double tr = dS[base + k * n + j] * cjr;
            double ti = -dS[base + k * n + j] * cji;
            if (n1 - j != j) {
                centry(l, j, n1 - j, cjr, cji);
                tr += dS[base + k * n + (n1 - j)] * cjr;
                ti += -dS[base + k * n + (n1 - j)] * cji;
            }
            centry(l, i, i, ckr, cki);
            jr += ckr * tr - cki * ti;
        }
        if (n1 - i != i) {
            int k = n1 - i;
            centry(l, j, j, cjr, cji);
            double tr = dS[base + k * n + j] * cjr;
            double ti = -dS[base + k * n + j] * cji;
            if (n1 - j != j) {
                centry(l, j, n1 - j, cjr, cji);
                tr += dS[base + k * n + (n1 - j)] * cjr;
                ti += -dS[base + k * n + (n1 - j)] * cji;
            }
            centry(l, i, n1 - i, ckr, cki);
            jr += ckr * tr - cki * ti;
        }
        Jout[base + i * n + j] = (float)jr;
    }
}

// ---------------------------------------------------------------------------
// Per-node: xm = node_feats @ W_msg1, only needed SPH rows {1,3,4,5,7,8}
// ---------------------------------------------------------------------------
__global__ __launch_bounds__(64) void k_xm(const float* __restrict__ nf,
                                           const float* __restrict__ m1,
                                           float* __restrict__ xm6)
{
    const int n = blockIdx.x;
    const int t = threadIdx.x;
    __shared__ float sx[SPHN * CHN];
    const float* xp = nf + (size_t)n * (SPHN * CHN);
#pragma unroll
    for (int i = 0; i < 9; ++i) sx[i * 64 + t] = xp[i * 64 + t];
    __syncthreads();
    float a0 = 0.f, a1 = 0.f, a2 = 0.f, a3 = 0.f, a4 = 0.f, a5 = 0.f;
    for (int c = 0; c < 64; ++c) {
        float m = m1[c * 64 + t];
        a0 += sx[1 * 64 + c] * m;
        a1 += sx[3 * 64 + c] * m;
        a2 += sx[4 * 64 + c] * m;
        a3 += sx[5 * 64 + c] * m;
        a4 += sx[7 * 64 + c] * m;
        a5 += sx[8 * 64 + c] * m;
    }
    float* op = xm6 + (size_t)n * 384;
    op[0 * 64 + t] = a0;
    op[1 * 64 + t] = a1;
    op[2 * 64 + t] = a2;
    op[3 * 64 + t] = a3;
    op[4 * 64 + t] = a4;
    op[5 * 64 + t] = a5;
}

__device__ __forceinline__ float siluf(float x) { return x / (1.f + expf(-x)); }

// ---------------------------------------------------------------------------
// Radial MLP tiled GEMM: 64 edges/block, 256 threads.
// rbf recomputed inline (saves 16 KB LDS -> 4 blocks/CU instead of 2).
// LDS: hT 32 KB + distS/envS 0.5 KB = 32.8 KB.
// ---------------------------------------------------------------------------
__global__ __launch_bounds__(256, 4) void k_rad(const float* __restrict__ evec,
                                                const float* __restrict__ w1,
                                                const float* __restrict__ b1,
                                                const float* __restrict__ w2,
                                                float* __restrict__ radg,
                                                int E)
{
    __shared__ float hT[128 * 64];    // [j][e]
    __shared__ float distS[64];
    __shared__ float envS[64];
    const int tid = threadIdx.x;
    const int base = blockIdx.x * 64;

    if (tid < 64) {
        int e = base + tid;
        float dist = 0.f;
        if (e < E) {
            float vx = evec[(size_t)e * 3 + 0];
            float vy = evec[(size_t)e * 3 + 1];
            float vz = evec[(size_t)e * 3 + 2];
            dist = sqrtf(vx * vx + vy * vy + vz * vz);
        }
        distS[tid] = dist;
        float dd = dist * (1.0f / 6.0f);
        float env = 0.f;
        if (dd < 1.0f) {
            float d2 = dd * dd;
            float d5 = d2 * d2 * dd;
            env = 1.0f - 21.0f * d5 + 35.0f * d5 * dd - 15.0f * d5 * d2;
        }
        envS[tid] = env;
    }
    __syncthreads();

    // Phase B: h = silu(rbf @ W1 + b1) -> hT[j][e]; rbf recomputed per-thread
    {
        const int eg = tid & 15;        // 16 edge-groups of 4
        const int jg = tid >> 4;        // 16 j-groups of 8
        const float d0 = distS[eg * 4 + 0];
        const float d1 = distS[eg * 4 + 1];
        const float d2 = distS[eg * 4 + 2];
        const float d3 = distS[eg * 4 + 3];
        float hacc[4][8];
        float4 b0 = *(const float4*)&b1[jg * 8];
        float4 b4 = *(const float4*)&b1[jg * 8 + 4];
#pragma unroll
        for (int ee = 0; ee < 4; ++ee) {
            hacc[ee][0] = b0.x; hacc[ee][1] = b0.y; hacc[ee][2] = b0.z; hacc[ee][3] = b0.w;
            hacc[ee][4] = b4.x; hacc[ee][5] = b4.y; hacc[ee][6] = b4.z; hacc[ee][7] = b4.w;
        }
        const float step = 6.0f / 63.0f;
#pragma unroll 4
        for (int k = 0; k < 64; ++k) {
            float4 wa = *(const float4*)&w1[k * 128 + jg * 8];
            float4 wb = *(const float4*)&w1[k * 128 + jg * 8 + 4];
            float ok = step * (float)k;
            float f0 = d0 - ok, f1 = d1 - ok, f2 = d2 - ok, f3 = d3 - ok;
            float r[4];
            r[0] = __expf(-55.125f * f0 * f0);
            r[1] = __expf(-55.125f * f1 * f1);
            r[2] = __expf(-55.125f * f2 * f2);
            r[3] = __expf(-55.125f * f3 * f3);
#pragma unroll
            for (int ee = 0; ee < 4; ++ee) {
                hacc[ee][0] += r[ee] * wa.x;
                hacc[ee][1] += r[ee] * wa.y;
                hacc[ee][2] += r[ee] * wa.z;
                hacc[ee][3] += r[ee] * wa.w;
                hacc[ee][4] += r[ee] * wb.x;
                hacc[ee][5] += r[ee] * wb.y;
                hacc[ee][6] += r[ee] * wb.z;
                hacc[ee][7] += r[ee] * wb.w;
            }
        }
#pragma unroll
        for (int jj = 0; jj < 8; ++jj) {
            float4 hv;
            hv.x = siluf(hacc[0][jj]);
            hv.y = siluf(hacc[1][jj]);
            hv.z = siluf(hacc[2][jj]);
            hv.w = siluf(hacc[3][jj]);
            *(float4*)&hT[(jg * 8 + jj) * 64 + eg * 4] = hv;
        }
    }
    __syncthreads();

    // Phase C: rad = h @ W2 * env
    {
        const int eg = tid >> 4;
        const int tg = tid & 15;
        float acc[4][4];
#pragma unroll
        for (int ee = 0; ee < 4; ++ee)
#pragma unroll
            for (int tt = 0; tt < 4; ++tt) acc[ee][tt] = 0.f;
#pragma unroll 4
        for (int j = 0; j < 128; ++j) {
            float4 wv = *(const float4*)&w2[j * 64 + tg * 4];
            float4 hv = *(const float4*)&hT[j * 64 + eg * 4];
            float h[4] = {hv.x, hv.y, hv.z, hv.w};
#pragma unroll
            for (int ee = 0; ee < 4; ++ee) {
                acc[ee][0] += h[ee] * wv.x;
                acc[ee][1] += h[ee] * wv.y;
                acc[ee][2] += h[ee] * wv.z;
                acc[ee][3] += h[ee] * wv.w;
            }
        }
#pragma unroll
        for (int ee = 0; ee < 4; ++ee) {
            int e = base + eg * 4 + ee;
            if (e < E) {
                float envv = envS[eg * 4 + ee];
                float4 o;
                o.x = acc[ee][0] * envv;
                o.y = acc[ee][1] * envv;
                o.z = acc[ee][2] * envv;
                o.w = acc[ee][3] * envv;
                *(float4*)&radg[(size_t)e * 64 + tg * 4] = o;
            }
        }
    }
}

// ---------------------------------------------------------------------------
// Per-edge Wigner Q: ONE THREAD PER EDGE (all lanes active), factored build:
//   A  = (rows {non-center}) of J*Zb   : A[a][m]  = J[r][m]*cb[m] + J[r][n1-m]*sb[n1-m]
//   Bc = (cols {non-center}) of J*Zc   : Bc[m][b] = J[m][c]*cz[c] + J[m][n1-c]*sz[c]
//   W  = A*Bc ;  Q = W^T W
// Histogram of dst folded in. Qe layout identical to before:
//   [0..3] Q1 over rows/cols {0,2} ; [4..19] Q2 over rows/cols {0,1,3,4}.
// ---------------------------------------------------------------------------
__global__ __launch_bounds__(256, 4) void k_wigE(const float* __restrict__ evec,
                                                 const int* __restrict__ eidx,
                                                 const float* __restrict__ Jc,
                                                 float* __restrict__ Qe,
                                                 int* __restrict__ counts, int E)
{
    __shared__ float sJ[34];
    const int tid = threadIdx.x;
    if (tid < 34) sJ[tid] = Jc[tid];
    __syncthreads();

    const int e = blockIdx.x * 256 + tid;
    if (e >= E) return;

    float vx = evec[(size_t)e * 3 + 0];
    float vy = evec[(size_t)e * 3 + 1];
    float vz = evec[(size_t)e * 3 + 2];
    float dist = sqrtf(vx * vx + vy * vy + vz * vz);
    float inv = 1.0f / fmaxf(dist, 1e-7f);
    float xn = fminf(fmaxf(vx * inv, -1.f), 1.f);
    float yn = fminf(fmaxf(vy * inv, -1.f), 1.f);
    float zn = fminf(fmaxf(vz * inv, -1.f), 1.f);
    float beta = acosf(fminf(fmaxf(yn, -1.f + 1e-7f), 1.f - 1e-7f));
    float alpha = atan2f(xn, zn);
    const float bA = -beta;
    const float cA = -alpha;

    atomicAdd(&counts[eidx[E + e]], 1);

    float* qo = Qe + (size_t)e * 20;

    // ---- l = 1 (3x3, J = sJ[0..8]) ----
    {
        const float* J1 = sJ;
        float cb[3], sb[3], cz[3], sz[3];
#pragma unroll
        for (int k = 0; k < 3; ++k) {
            __sincosf((float)(1 - k) * bA, &sb[k], &cb[k]);
            __sincosf((float)(k - 1) * cA, &sz[k], &cz[k]);
        }
        cb[1] = 0.f; cz[1] = 0.f;
        float A[2][3], Bc[3][2], W[2][2];
#pragma unroll
        for (int a = 0; a < 2; ++a) {
            int r = a * 2;
#pragma unroll
            for (int m = 0; m < 3; ++m)
                A[a][m] = J1[r * 3 + m] * cb[m] + J1[r * 3 + (2 - m)] * sb[2 - m];
        }
#pragma unroll
        for (int m = 0; m < 3; ++m)
#pragma unroll
            for (int b = 0; b < 2; ++b) {
                int c = b * 2;
                Bc[m][b] = J1[m * 3 + c] * cz[c] + J1[m * 3 + (2 - c)] * sz[c];
            }
#pragma unroll
        for (int a = 0; a < 2; ++a)
#pragma unroll
            for (int b = 0; b < 2; ++b) {
                float w = 0.f;
#pragma unroll
                for (int m = 0; m < 3; ++m) w += A[a][m] * Bc[m][b];
                W[a][b] = w;
            }
        float4 q;
        q.x = W[0][0] * W[0][0] + W[1][0] * W[1][0];
        q.y = W[0][0] * W[0][1] + W[1][0] * W[1][1];
        q.z = W[0][1] * W[0][0] + W[1][1] * W[1][0];
        q.w = W[0][1] * W[0][1] + W[1][1] * W[1][1];
        *(float4*)&qo[0] = q;
    }

    // ---- l = 2 (5x5, J = sJ[9..33]) ----
    {
        const float* J2 = sJ + 9;
        float cb[5], sb[5], cz[5], sz[5];
#pragma unroll
        for (int k = 0; k < 5; ++k) {
            __sincosf((float)(2 - k) * bA, &sb[k], &cb[k]);
            __sincosf((float)(k - 2) * cA, &sz[k], &cz[k]);
        }
        cb[2] = 0.f; cz[2] = 0.f;
        const int rmap[4] = {0, 1, 3, 4};
        float A[4][5], Bc[5][4], W[4][4];
#pragma unroll
        for (int a = 0; a < 4; ++a) {
            int r = rmap[a];
#pragma unroll
            for (int m = 0; m < 5; ++m)
                A[a][m] = J2[r * 5 + m] * cb[m] + J2[r * 5 + (4 - m)] * sb[4 - m];
        }
#pragma unroll
        for (int m = 0; m < 5; ++m)
#pragma unroll
            for (int b = 0; b < 4; ++b) {
                int c = rmap[b];
                Bc[m][b] = J2[m * 5 + c] * cz[c] + J2[m * 5 + (4 - c)] * sz[c];
            }
#pragma unroll
        for (int a = 0; a < 4; ++a)
#pragma unroll
            for (int b = 0; b < 4; ++b) {
                float w = 0.f;
#pragma unroll
                for (int m = 0; m < 5; ++m) w += A[a][m] * Bc[m][b];
                W[a][b] = w;
            }
#pragma unroll
        for (int a = 0; a < 4; ++a) {
            float4 q;
            q.x = W[0][a] * W[0][0] + W[1][a] * W[1][0] + W[2][a] * W[2][0] + W[3][a] * W[3][0];
            q.y = W[0][a] * W[0][1] + W[1][a] * W[1][1] + W[2][a] * W[2][1] + W[3][a] * W[3][1];
            q.z = W[0][a] * W[0][2] + W[1][a] * W[1][2] + W[2][a] * W[2][2] + W[3][a] * W[3][2];
            q.w = W[0][a] * W[0][3] + W[1][a] * W[1][3] + W[2][a] * W[2][3] + W[3][a] * W[3][3];
            *(float4*)&qo[4 + a * 4] = q;   // row a of Q2 (Q symmetric, = col a)
        }
    }
}

// ---------------------------------------------------------------------------
// Exclusive scan of counts[N] -> offsets/cursors, offsets[N]=total.
// ---------------------------------------------------------------------------
__global__ __launch_bounds__(1024) void k_scan(const int* __restrict__ counts,
                                               int* __restrict__ offsets,
                                               int* __restrict__ cursors, int N)
{
    __shared__ int wsum[16];
    __shared__ int wpre[16];
    const int tid = threadIdx.x;
    const int lane = tid & 63;
    const int wid = tid >> 6;
    const int per = (N + 1023) >> 10;
    const int begin = tid * per;
    const int endi = (begin + per < N) ? (begin + per) : N;

    int s = 0;
    for (int i = begin; i < endi; ++i) s += counts[i];

    int inc = s;
#pragma unroll
    for (int off = 1; off < 64; off <<= 1) {
        int u = __shfl_up(inc, off, 64);
        if (lane >= off) inc += u;
    }
    if (lane == 63) wsum[wid] = inc;
    __syncthreads();
    if (wid == 0) {
        int v = (lane < 16) ? wsum[lane] : 0;
        int winc = v;
#pragma unroll
        for (int off = 1; off < 16; off <<= 1) {
            int u = __shfl_up(winc, off, 64);
            if (lane >= off) winc += u;
        }
        if (lane < 16) wpre[lane] = winc - v;
    }
    __syncthreads();
    int run = wpre[wid] + (inc - s);
    for (int i = begin; i < endi; ++i) {
        int c = counts[i];
        offsets[i] = run;
        cursors[i] = run;
        run += c;
    }
    if (endi == N && begin < N) offsets[N] = run;
}

__global__ __launch_bounds__(256) void k_scatter(const int* __restrict__ eidx,
                                                 int* __restrict__ cursors,
                                                 int* __restrict__ perm, int E)
{
    int e = blockIdx.x * 256 + threadIdx.x;
    if (e < E) {
        int pos = atomicAdd(&cursors[eidx[E + e]], 1);
        perm[pos] = e;
    }
}

// ---------------------------------------------------------------------------
// Per-dst-node gather + register accumulate + fused M2/RMS/gamma finalize.
// ---------------------------------------------------------------------------
__global__ __launch_bounds__(64) void k_gather_fin(const int* __restrict__ eidx,
                                                   const int* __restrict__ offsets,
                                                   const int* __restrict__ perm,
                                                   const float* __restrict__ Qe,
                                                   const float* __restrict__ radg,
                                                   const float* __restrict__ xm6,
                                                   const float* __restrict__ m2,
                                                   const float* __restrict__ gam,
                                                   float* __restrict__ out, int E)
{
    const int n = blockIdx.x;
    const int t = threadIdx.x;
    const int start = offsets[n];
    const int end = offsets[n + 1];

    float a1 = 0.f, a3 = 0.f, a4 = 0.f, a5 = 0.f, a7 = 0.f, a8 = 0.f;
    for (int i = start; i < end; ++i) {
        const int e = perm[i];
        const int src = eidx[e];
        const float* q = Qe + (size_t)e * 20;
        float4 q0 = *(const float4*)&q[0];
        float4 q1 = *(const float4*)&q[4];
        float4 q2 = *(const float4*)&q[8];
        float4 q3 = *(const float4*)&q[12];
        float4 q4 = *(const float4*)&q[16];
        const float rad = radg[(size_t)e * 64 + t];
        const float* xs = xm6 + (size_t)src * 384;
        float x1 = xs[0 * 64 + t];
        float x3 = xs[1 * 64 + t];
        float x4 = xs[2 * 64 + t];
        float x5 = xs[3 * 64 + t];
        float x7 = xs[4 * 64 + t];
        float x8 = xs[5 * 64 + t];
        a1 += rad * (q0.x * x1 + q0.y * x3);
        a3 += rad * (q0.z * x1 + q0.w * x3);
        a4 += rad * (q1.x * x4 + q1.y * x5 + q1.z * x7 + q1.w * x8);
        a5 += rad * (q2.x * x4 + q2.y * x5 + q2.z * x7 + q2.w * x8);
        a7 += rad * (q3.x * x4 + q3.y * x5 + q3.z * x7 + q3.w * x8);
        a8 += rad * (q4.x * x4 + q4.y * x5 + q4.z * x7 + q4.w * x8);
    }

    __shared__ float sa[6 * 64];
    sa[0 * 64 + t] = a1;
    sa[1 * 64 + t] = a3;
    sa[2 * 64 + t] = a4;
    sa[3 * 64 + t] = a5;
    sa[4 * 64 + t] = a7;
    sa[5 * 64 + t] = a8;
    __syncthreads();
    float v0 = 0.f, v1 = 0.f, v2 = 0.f, v3 = 0.f, v4 = 0.f, v5 = 0.f;
    for (int c = 0; c < 64; ++c) {
        float m = m2[c * 64 + t];
        v0 += sa[0 * 64 + c] * m;
        v1 += sa[1 * 64 + c] * m;
        v2 += sa[2 * 64 + c] * m;
        v3 += sa[3 * 64 + c] * m;
        v4 += sa[4 * 64 + c] * m;
        v5 += sa[5 * 64 + c] * m;
    }
    float ss = v0 * v0 + v1 * v1 + v2 * v2 + v3 * v3 + v4 * v4 + v5 * v5;
    float rms = sqrtf(ss * (1.0f / 9.0f) + 1e-7f);
    float sc = gam[t] / rms;
    float* op = out + (size_t)n * 576;
    op[0 * 64 + t] = 0.f;
    op[2 * 64 + t] = 0.f;
    op[6 * 64 + t] = 0.f;
    op[1 * 64 + t] = v0 * sc;
    op[3 * 64 + t] = v1 * sc;
    op[4 * 64 + t] = v2 * sc;
    op[5 * 64 + t] = v3 * sc;
    op[7 * 64 + t] = v4 * sc;
    op[8 * 64 + t] = v5 * sc;
}

// ---------------------------------------------------------------------------
// Legacy fallback path (small ws): Wigner entry + atomic scatter + finalize
// ---------------------------------------------------------------------------
__device__ __forceinline__ float wig_entry(int l, int i, int j, float bA, float cA,
                                           const float* __restrict__ J, int n)
{
    if (i == l) return 0.f;
    const int j2 = 2 * l - j;
    float Pij = 0.f, Pij2 = 0.f;
    for (int k = 0; k < n; ++k) {
        float sbk, cbk;
        __sincosf((float)(l - k) * bA, &sbk, &cbk);
        if (k == l) cbk = 0.f;
        float zj  = cbk * J[k * n + j]  + sbk * J[(2 * l - k) * n + j];
        float zj2 = cbk * J[k * n + j2] + sbk * J[(2 * l - k) * n + j2];
        Pij  += J[i * n + k] * zj;
        Pij2 += J[i * n + k] * zj2;
    }
    float s_, c_;
    __sincosf((float)(l - j) * cA, &s_, &c_);
    float czj = (j == l) ? 0.f : c_;
    float szj = -s_;
    return Pij * czj + Pij2 * szj;
}

__global__ __launch_bounds__(64) void k_edge2(const float* __restrict__ evec,
                                              const int* __restrict__ eidx,
                                              const float* __restrict__ radg,
                                              const float* __restrict__ Jc,
                                              const float* __restrict__ xm6,
                                              float* __restrict__ acc, int E)
{
    const int e = blockIdx.x;
    const int t = threadIdx.x;
    __shared__ float s_W1[9], s_W2[25], s_Q1[9], s_Q2[25];

    float vx = evec[(size_t)e * 3 + 0];
    float vy = evec[(size_t)e * 3 + 1];
    float vz = evec[(size_t)e * 3 + 2];
    float dist = sqrtf(vx * vx + vy * vy + vz * vz);
    float inv = 1.0f / fmaxf(dist, 1e-7f);
    float xn = fminf(fmaxf(vx * inv, -1.f), 1.f);
    float yn = fminf(fmaxf(vy * inv, -1.f), 1.f);
    float zn = fminf(fmaxf(vz * inv, -1.f), 1.f);
    float beta = acosf(fminf(fmaxf(yn, -1.f + 1e-7f), 1.f - 1e-7f));
    float alpha = atan2f(xn, zn);
    float bA = -beta;
    float cA = -alpha;

    if (t < 25) {
        s_W2[t] = wig_entry(2, t / 5, t % 5, bA, cA, Jc + 9, 5);
    } else if (t >= 32 && t < 41) {
        int u = t - 32;
        s_W1[u] = wig_entry(1, u / 3, u % 3, bA, cA, Jc, 3);
    }
    __syncthreads();

    if (t < 25) {
        int i = t / 5, j = t % 5;
        float qv = 0.f;
#pragma unroll
        for (int k = 0; k < 5; ++k) qv += s_W2[k * 5 + i] * s_W2[k * 5 + j];
        s_Q2[t] = qv;
    } else if (t >= 32 && t < 41) {
        int u = t - 32;
        int i = u / 3, j = u % 3;
        float qv = 0.f;
#pragma unroll
        for (int k = 0; k < 3; ++k) qv += s_W1[k * 3 + i] * s_W1[k * 3 + j];
        s_Q1[u] = qv;
    }
    __syncthreads();

    const float rad = radg[(size_t)e * 64 + t];
    const int src = eidx[e];
    const int dst = eidx[E + e];
    const float* xs = xm6 + (size_t)src * 384;
    float x1 = xs[0 * 64 + t];
    float x3 = xs[1 * 64 + t];
    float x4 = xs[2 * 64 + t];
    float x5 = xs[3 * 64 + t];
    float x7 = xs[4 * 64 + t];
    float x8 = xs[5 * 64 + t];

    float m1v = rad * (s_Q1[0] * x1 + s_Q1[2] * x3);
    float m3v = rad * (s_Q1[6] * x1 + s_Q1[8] * x3);
    float m4v = rad * (s_Q2[0]  * x4 + s_Q2[1]  * x5 + s_Q2[3]  * x7 + s_Q2[4]  * x8);
    float m5v = rad * (s_Q2[5]  * x4 + s_Q2[6]  * x5 + s_Q2[8]  * x7 + s_Q2[9]  * x8);
    float m7v = rad * (s_Q2[15] * x4 + s_Q2[16] * x5 + s_Q2[18] * x7 + s_Q2[19] * x8);
    float m8v = rad * (s_Q2[20] * x4 + s_Q2[21] * x5 + s_Q2[23] * x7 + s_Q2[24] * x8);

    float* ad = acc + (size_t)dst * 576;
    atomicAdd(ad + 1 * 64 + t, m1v);
    atomicAdd(ad + 3 * 64 + t, m3v);
    atomicAdd(ad + 4 * 64 + t, m4v);
    atomicAdd(ad + 5 * 64 + t, m5v);
    atomicAdd(ad + 7 * 64 + t, m7v);
    atomicAdd(ad + 8 * 64 + t, m8v);
}

__global__ __launch_bounds__(64) void k_fin(const float* __restrict__ m2,
                                            const float* __restrict__ gam,
                                            float* __restrict__ out)
{
    const int n = blockIdx.x;
    const int t = threadIdx.x;
    __shared__ float sa[6 * 64];
    float* op = out + (size_t)n * 576;
    sa[0 * 64 + t] = op[1 * 64 + t];
    sa[1 * 64 + t] = op[3 * 64 + t];
    sa[2 * 64 + t] = op[4 * 64 + t];
    sa[3 * 64 + t] = op[5 * 64 + t];
    sa[4 * 64 + t] = op[7 * 64 + t];
    sa[5 * 64 + t] = op[8 * 64 + t];
    __syncthreads();
    float v0 = 0.f, v1 = 0.f, v2 = 0.f, v3 = 0.f, v4 = 0.f, v5 = 0.f;
    for (int c = 0; c < 64; ++c) {
        float m = m2[c * 64 + t];
        v0 += sa[0 * 64 + c] * m;
        v1 += sa[1 * 64 + c] * m;
        v2 += sa[2 * 64 + c] * m;
        v3 += sa[3 * 64 + c] * m;
        v4 += sa[4 * 64 + c] * m;
        v5 += sa[5 * 64 + c] * m;
    }
    float ss = v0 * v0 + v1 * v1 + v2 * v2 + v3 * v3 + v4 * v4 + v5 * v5;
    float rms = sqrtf(ss * (1.0f / 9.0f) + 1e-7f);
    float sc = gam[t] / rms;
    op[0 * 64 + t] = 0.f;
    op[2 * 64 + t] = 0.f;
    op[6 * 64 + t] = 0.f;
    op[1 * 64 + t] = v0 * sc;
    op[3 * 64 + t] = v1 * sc;
    op[4 * 64 + t] = v2 * sc;
    op[5 * 64 + t] = v3 * sc;
    op[7 * 64 + t] = v4 * sc;
    op[8 * 64 + t] = v5 * sc;
}

static inline size_t align256(size_t x) { return (x + 255) & ~(size_t)255; }

extern "C" void kernel_launch(void* const* d_in, const int* in_sizes, int n_in,
                              void* d_out, int out_size, void* d_ws, size_t ws_size,
                              hipStream_t stream)
{
    const float* nf  = (const float*)d_in[0];
    const float* ev  = (const float*)d_in[1];
    const int*   ei  = (const int*)d_in[2];
    const float* w1  = (const float*)d_in[3];
    const float* b1  = (const float*)d_in[4];
    const float* w2  = (const float*)d_in[5];
    const float* m1  = (const float*)d_in[6];
    const float* m2  = (const float*)d_in[7];
    const float* gam = (const float*)d_in[8];

    const int N = in_sizes[0] / (SPHN * CHN);
    const int E = in_sizes[1] / 3;

    float* out = (float*)d_out;
    char* base = (char*)d_ws;
    size_t off = 0;
    float* Jc = (float*)(base + off);            off += align256(34 * sizeof(float));
    float* xm6 = (float*)(base + off);           off += align256((size_t)N * 384 * sizeof(float));
    float* radg = (float*)(base + off);          off += align256((size_t)E * 64 * sizeof(float));
    size_t need_old = off;                       // through radg
    float* Qe = (float*)(base + off);            off += align256((size_t)E * 20 * sizeof(float));
    int* counts = (int*)(base + off);            off += align256((size_t)N * sizeof(int));
    int* offsets = (int*)(base + off);           off += align256((size_t)(N + 1) * sizeof(int));
    int* cursors = (int*)(base + off);           off += align256((size_t)N * sizeof(int));
    int* perm = (int*)(base + off);              off += align256((size_t)E * sizeof(int));
    size_t need_new = off;

    if (ws_size >= need_new) {
        hipLaunchKernelGGL(k_setup, dim3((N + 255) / 256), dim3(256), 0, stream,
                           Jc, counts, N);
        hipLaunchKernelGGL(k_xm, dim3(N), dim3(64), 0, stream, nf, m1, xm6);
        hipLaunchKernelGGL(k_rad, dim3((E + 63) / 64), dim3(256), 0, stream,
                           ev, w1, b1, w2, radg, E);
        hipLaunchKernelGGL(k_wigE, dim3((E + 255) / 256), dim3(256), 0, stream,
                           ev, ei, Jc, Qe, counts, E);
        hipLaunchKernelGGL(k_scan, dim3(1), dim3(1024), 0, stream,
                           counts, offsets, cursors, N);
        hipLaunchKernelGGL(k_scatter, dim3((E + 255) / 256), dim3(256), 0, stream,
                           ei, cursors, perm, E);
        hipLaunchKernelGGL(k_gather_fin, dim3(N), dim3(64), 0, stream,
                           ei, offsets, perm, Qe, radg, xm6, m2, gam, out, E);
    } else if (ws_size >= need_old) {
        hipLaunchKernelGGL(k_setup, dim3(1), dim3(256), 0, stream,
                           Jc, (int*)nullptr, 0);
        hipLaunchKernelGGL(k_xm, dim3(N), dim3(64), 0, stream, nf, m1, xm6);
        hipMemsetAsync(d_out, 0, (size_t)out_size * sizeof(float), stream);
        hipLaunchKernelGGL(k_rad, dim3((E + 63) / 64), dim3(256), 0, stream,
                           ev, w1, b1, w2, radg, E);
        hipLaunchKernelGGL(k_edge2, dim3(E), dim3(64), 0, stream,
                           ev, ei, radg, Jc, xm6, out, E);
        hipLaunchKernelGGL(k_fin, dim3(N), dim3(64), 0, stream, m2, gam, out);
    }
}